// Round 9
// baseline (277.638 us; speedup 1.0000x reference)
//
#include <hip/hip_runtime.h>
#include <hip/hip_bf16.h>

#define BATCH 4
#define CDIM  256
#define NTOK  4096
#define THREE (3*CDIM)
#define VROWS 272   // 256 V channels + fg row at 256 (257..271 unused)

typedef unsigned short u16;
typedef __attribute__((ext_vector_type(4))) float f32x4;
typedef __attribute__((ext_vector_type(8))) short bf16x8;

#define AS1 __attribute__((address_space(1)))
#define AS3 __attribute__((address_space(3)))

__device__ __forceinline__ u16 f2bf(float x) {
  unsigned int u = __float_as_uint(x);
  unsigned int r = (u + 0x7fffu + ((u >> 16) & 1u)) >> 16;   // RTNE
  return (u16)r;
}
__device__ __forceinline__ float bf2f(u16 v) {
  return __uint_as_float(((unsigned int)v) << 16);
}

__device__ __forceinline__ void gload_lds16(const u16* g, u16* l) {
  __builtin_amdgcn_global_load_lds((AS1 const void*)g, (AS3 void*)l, 16, 0, 0);
}

// ---------------- K1: weights -> bf16; fg -> bf16 row in Vt ----------------
__global__ void k_prep(const float* __restrict__ Wqkv, const float* __restrict__ Wproj,
                       const int* __restrict__ fg,
                       u16* __restrict__ wq, u16* __restrict__ wp,
                       u16* __restrict__ Vt) {
  int i = blockIdx.x * 256 + threadIdx.x;
  const int nq = THREE * CDIM;          // 196608
  const int np = CDIM * CDIM;           // 65536
  const int nf = BATCH * NTOK;          // 16384 (fg row c=256)
  if (i < nq) { wq[i] = f2bf(Wqkv[i]); return; }
  int j = i - nq;
  if (j < np) { wp[j] = f2bf(Wproj[j]); return; }
  int k = j - np;
  if (k < nf) {
    int b = k >> 12, key = k & (NTOK - 1);
    Vt[((size_t)b * VROWS + 256) * NTOK + key] = fg[k] ? 0x3F80 : 0;  // bf16 1.0/0.0
  }
}

// ---------------- K2: qkv GEMM with fused x-transpose ----------------
// A = xf [N][C] built on the fly from x [C][N] (f32, coalesced) via in-LDS transpose.
// Q (x log2e/16), K row-major; V^T [c][key], fg-zeroed.
__global__ __launch_bounds__(256) void k_qkv(const float* __restrict__ x, const u16* __restrict__ wq,
                                             const int* __restrict__ fg,
                                             u16* __restrict__ Qm, u16* __restrict__ Km,
                                             u16* __restrict__ Vt) {
  __shared__ float T[64][132];     // x tile [c 64][n 128+pad] f32
  __shared__ u16 Al[128][72];      // xf tile [n 128][c 64+pad] bf16
  __shared__ u16 Bl[128][72];
  int n0 = blockIdx.x * 128;
  int d0 = blockIdx.y * 128;
  int b  = blockIdx.z;
  int tid = threadIdx.x;
  int lane = tid & 63, w = tid >> 6;
  int lo = lane & 15, hi = lane >> 4;
  int wm = w >> 1, wn = w & 1;
  f32x4 acc[4][4] = {};
  const float* xb = x + (size_t)b * CDIM * NTOK;
  const u16* Bb = wq + (size_t)d0 * CDIM;
  for (int kc = 0; kc < 256; kc += 64) {
    __syncthreads();
    // phase1: coalesced f32 loads of x[kc..kc+63][n0..n0+127] into T; B tile into Bl
    {
      int cs = tid >> 4;            // 0..15
      int n4 = (tid & 15) * 4;      // 0..60
#pragma unroll
      for (int i = 0; i < 4; ++i) {
        int c = i * 16 + cs;
        const float* src = xb + (size_t)(kc + c) * NTOK + n0 + n4;
        *(float4*)&T[c][n4]      = *(const float4*)(src);
        *(float4*)&T[c][n4 + 64] = *(const float4*)(src + 64);
      }
#pragma unroll
      for (int i = 0; i < 4; ++i) {
        int cid = i * 256 + tid;
        int row = cid >> 3, cc = cid & 7;
        *(uint4*)&Bl[row][cc * 8] = *(const uint4*)(Bb + (size_t)row * CDIM + kc + cc * 8);
      }
    }
    __syncthreads();
    // phase2: transpose-convert T -> Al[n][c] bf16
    {
      int n = tid & 127, ch = tid >> 7;
#pragma unroll
      for (int j = 0; j < 32; ++j) {
        int c = ch * 32 + j;
        Al[n][c] = f2bf(T[c][n]);
      }
    }
    __syncthreads();
#pragma unroll
    for (int kk = 0; kk < 2; ++kk) {
      bf16x8 af[4], bfr[4];
#pragma unroll
      for (int mi = 0; mi < 4; ++mi) af[mi]  = *(const bf16x8*)&Al[wm * 64 + mi * 16 + lo][kk * 32 + hi * 8];
#pragma unroll
      for (int ni = 0; ni < 4; ++ni) bfr[ni] = *(const bf16x8*)&Bl[wn * 64 + ni * 16 + lo][kk * 32 + hi * 8];
#pragma unroll
      for (int mi = 0; mi < 4; ++mi)
#pragma unroll
        for (int ni = 0; ni < 4; ++ni)
          acc[mi][ni] = __builtin_amdgcn_mfma_f32_16x16x32_bf16(af[mi], bfr[ni], acc[mi][ni], 0, 0, 0);
    }
  }
  int seg = d0 >> 8;   // 0=Q 1=K 2=V
  const float QSC = 0.0625f * 1.4426950408889634f;   // (1/sqrt(C)) * log2(e)
#pragma unroll
  for (int mi = 0; mi < 4; ++mi) {
    int nbase = n0 + wm * 64 + mi * 16 + hi * 4;
#pragma unroll
    for (int ni = 0; ni < 4; ++ni) {
      int d = d0 + wn * 64 + ni * 16 + lo;
      if (seg == 0) {
#pragma unroll
        for (int r = 0; r < 4; ++r)
          Qm[((size_t)b * NTOK + nbase + r) * CDIM + d] = f2bf(acc[mi][ni][r] * QSC);
      } else if (seg == 1) {
        int dk = d - 256;
#pragma unroll
        for (int r = 0; r < 4; ++r)
          Km[((size_t)b * NTOK + nbase + r) * CDIM + dk] = f2bf(acc[mi][ni][r]);
      } else {
        int dv = d - 512;
        ushort4 pk;
        pk.x = fg[b * NTOK + nbase + 0] ? f2bf(acc[mi][ni][0]) : (u16)0;
        pk.y = fg[b * NTOK + nbase + 1] ? f2bf(acc[mi][ni][1]) : (u16)0;
        pk.z = fg[b * NTOK + nbase + 2] ? f2bf(acc[mi][ni][2]) : (u16)0;
        pk.w = fg[b * NTOK + nbase + 3] ? f2bf(acc[mi][ni][3]) : (u16)0;
        *(ushort4*)&Vt[((size_t)b * VROWS + dv) * NTOK + nbase] = pk;
      }
    }
  }
}

// ---------------- K3: flash attention, split-K(4), fixed-max, mask-in-V ----------------
// grid = 512 blocks; 4 waves x 32 q-rows; KBLK=32. R6 schedule: stage next tile at
// top of body, ONE __syncthreads per iter (implicit full drain covers residency).
// Static buffer pointers via manual 2x unroll. P = exp2(QK - 12); numerator mask via
// zeroed V rows; l = sum P*fg with the bf16 fg row staged in LDS.
__global__ __launch_bounds__(256, 2) void k_attn(const u16* __restrict__ Qm, const u16* __restrict__ Km,
                                                 const u16* __restrict__ Vt,
                                                 u16* __restrict__ pacc, float2* __restrict__ pml) {
  __shared__ u16 Kl[2][32 * 256];    // 16KB x2; row=512B, 16B-chunk ^= (row&7)<<4
  __shared__ u16 Vl[2][256 * 32];    // 16KB x2; row=64B (V^T [c][key]), chunk ^= row&3
  __shared__ u16 Pl[4][32 * 32];     // 2KB/wave; row=64B (P [q][key])
  __shared__ u16 fgl[1024];          // bf16 fg for this chunk's 1024 keys
  const float FM = 12.0f;            // fixed softmax max (log2 units)
  int nwg = gridDim.x;
  int cpx = nwg >> 3;
  int orig = blockIdx.x;
  int wg = (orig & 7) * cpx + (orig >> 3);   // bijective XCD swizzle (nwg % 8 == 0)
  int qt = wg & 31;
  int bs = wg >> 5;
  int s_k = bs & 3;
  int b   = bs >> 2;
  const int chunk = NTOK >> 2;               // 1024
  int koff  = s_k * chunk;
  const int iters = chunk >> 5;              // 32

  int tid = threadIdx.x;
  int lane = tid & 63, w = tid >> 6;
  int lo = lane & 15, hi = lane >> 4;
  int n0 = qt * 128 + w * 32;
  // Q: 32 rows x 256 in registers (64 VGPR)
  bf16x8 qf[2][8];
#pragma unroll
  for (int s = 0; s < 2; ++s) {
    const u16* qp = Qm + ((size_t)b * NTOK + n0 + s * 16 + lo) * CDIM + hi * 8;
#pragma unroll
    for (int ks = 0; ks < 8; ++ks) qf[s][ks] = *(const bf16x8*)(qp + ks * 32);
  }
  f32x4 acc[2][16] = {};
  float lsum[2][4] = {};
  const u16* kbase = Km + (size_t)b * NTOK * CDIM;
  const u16* vbase = Vt + (size_t)b * VROWS * NTOK;
  const u16* fgrow = vbase + (size_t)256 * NTOK;   // bf16 fg row
  int kc  = lane & 31;   // K staging: 16B chunk within row pair
  int krp = lane >> 5;
  int vr  = lane >> 2;   // V staging: row within 16-row tile
  int vc  = lane & 3;

  // stage K (4 insts/wave) + V (4 insts/wave) for key-block m0
  auto stage = [&](u16* Kb, u16* Vb, int m0) {
    u16* kld = Kb + w * 2048;
#pragma unroll
    for (int j = 0; j < 4; ++j) {
      int row = w * 8 + j * 2 + krp;
      int sb = (kc * 16) ^ ((row & 7) << 4);
      gload_lds16(kbase + (size_t)(m0 + row) * CDIM + (sb >> 1), kld + j * 512);
    }
#pragma unroll
    for (int j = 0; j < 4; ++j) {
      int idx = j * 4 + w;                 // 0..15 tiles of 16 rows
      int r = idx * 16 + vr;
      int d = vc ^ (r & 3);
      gload_lds16(vbase + (size_t)r * NTOK + m0 + d * 8, Vb + idx * 512);
    }
  };

  // one iteration: stage next at top (hidden under compute), single barrier at end
  auto body = [&](int it, const u16* Kcur, const u16* Vcur, u16* Kst, u16* Vst) {
    int m0 = koff + it * 32;
    if (it + 1 < iters) stage(Kst, Vst, m0 + 32);
    // S - FM = Q K^T - 12 (log2 domain)
    f32x4 sv[2][2];
#pragma unroll
    for (int s = 0; s < 2; ++s)
#pragma unroll
      for (int ni = 0; ni < 2; ++ni)
#pragma unroll
        for (int r = 0; r < 4; ++r) sv[s][ni][r] = -FM;
    __builtin_amdgcn_s_setprio(1);
#pragma unroll
    for (int ks = 0; ks < 8; ++ks) {
      bf16x8 kf[2];
#pragma unroll
      for (int ni = 0; ni < 2; ++ni) {
        int row = ni * 16 + lo;
        const char* kp = (const char*)Kcur + row * 512 + ((ks * 64 + hi * 16) ^ ((row & 7) << 4));
        kf[ni] = *(const bf16x8*)kp;
      }
#pragma unroll
      for (int s = 0; s < 2; ++s)
#pragma unroll
        for (int ni = 0; ni < 2; ++ni)
          sv[s][ni] = __builtin_amdgcn_mfma_f32_16x16x32_bf16(qf[s][ks], kf[ni], sv[s][ni], 0, 0, 0);
    }
    __builtin_amdgcn_s_setprio(0);
    // P = exp2(S-FM); l += P * fg (fg from LDS); P -> bf16 -> per-wave swizzled LDS
    float fgm[2];
    fgm[0] = bf2f(fgl[it * 32 + lo]);
    fgm[1] = bf2f(fgl[it * 32 + 16 + lo]);
#pragma unroll
    for (int s = 0; s < 2; ++s)
#pragma unroll
      for (int ni = 0; ni < 2; ++ni)
#pragma unroll
        for (int r = 0; r < 4; ++r) {
          float e = exp2f(sv[s][ni][r]);
          lsum[s][r] += e * fgm[ni];
          int q = s * 16 + hi * 4 + r;
          int byteoff = q * 64 + ((ni * 32 + lo * 2) ^ ((q & 12) << 2));
          *(u16*)((char*)&Pl[w][0] + byteoff) = f2bf(e);
        }
    // PV: A from Pl (wave-private, DS wave-ordered), B from Vl
    bf16x8 pa[2];
#pragma unroll
    for (int s = 0; s < 2; ++s) {
      const char* pp = (const char*)&Pl[w][0] + (s * 16 + lo) * 64 + ((hi * 16) ^ ((lo & 12) << 2));
      pa[s] = *(const bf16x8*)pp;
    }
    __builtin_amdgcn_s_setprio(1);
#pragma unroll
    for (int cf = 0; cf < 16; ++cf) {
      const char* vp = (const char*)Vcur + (cf * 16 + lo) * 64 + ((hi ^ (lo & 3)) << 4);
      bf16x8 vb = *(const bf16x8*)vp;
#pragma unroll
      for (int s = 0; s < 2; ++s)
        acc[s][cf] = __builtin_amdgcn_mfma_f32_16x16x32_bf16(pa[s], vb, acc[s][cf], 0, 0, 0);
    }
    __builtin_amdgcn_s_setprio(0);
    __syncthreads();   // full drain: next-tile loads resident; cur buffers free
  };

  // prologue: fg chunk (waves 0,1: one load each) + tile 0
  if (w < 2) gload_lds16(fgrow + koff + w * 512 + lane * 8, &fgl[w * 512 + lane * 8]);
  stage(&Kl[0][0], &Vl[0][0], koff);
  __syncthreads();
  for (int it = 0; it < iters; it += 2) {
    body(it,     &Kl[0][0], &Vl[0][0], &Kl[1][0], &Vl[1][0]);
    body(it + 1, &Kl[1][0], &Vl[1][0], &Kl[0][0], &Vl[0][0]);
  }
  // one-time cross-lane l reduction (sum over the 16 lanes sharing hi)
  float ls[2][4];
#pragma unroll
  for (int s = 0; s < 2; ++s)
#pragma unroll
    for (int r = 0; r < 4; ++r) {
      float t = lsum[s][r];
      t += __shfl_xor(t, 1); t += __shfl_xor(t, 2);
      t += __shfl_xor(t, 4); t += __shfl_xor(t, 8);
      ls[s][r] = t;
    }
  // epilogue: bf16 unnormalized partials + (m=FM, l) per row
  u16* pb = pacc + (((size_t)s_k * BATCH + b) * NTOK + n0) * CDIM;
  float2* pm = pml + ((size_t)s_k * BATCH + b) * NTOK + n0;
#pragma unroll
  for (int s = 0; s < 2; ++s)
#pragma unroll
    for (int r = 0; r < 4; ++r) {
      int row = s * 16 + hi * 4 + r;
#pragma unroll
      for (int cf = 0; cf < 16; ++cf)
        pb[(size_t)row * CDIM + cf * 16 + lo] = f2bf(acc[s][cf][r]);
      if (lo == 0) {
        float2 v; v.x = FM; v.y = ls[s][r];
        pm[row] = v;
      }
    }
}

// ---------------- K4: fused combine + projection ----------------
// out[b][c][n] = b_proj[c] + sum_k h[b][n][k] Wp[c][k],  h = (sum_s pacc_s) / (sum_s l_s)
// (all split maxima equal FM -> combine weights are uniform 1/sum(l)).
__global__ __launch_bounds__(256) void k_proj(const u16* __restrict__ pacc,
                                              const float2* __restrict__ pml,
                                              const u16* __restrict__ wp,
                                              const float* __restrict__ bproj, float* __restrict__ out) {
  __shared__ u16 Al[128][72];
  __shared__ u16 Bl[128][72];
  __shared__ float invl[128];
  const int RN = BATCH * NTOK;
  int n0 = blockIdx.x * 128;
  int c0 = blockIdx.y * 128;
  int b  = blockIdx.z;
  int tid = threadIdx.x;
  int lane = tid & 63, w = tid >> 6;
  int lo = lane & 15, hi = lane >> 4;
  int wm = w >> 1, wn = w & 1;
  if (tid < 128) {
    float d = 0.0f;
#pragma unroll
    for (int s = 0; s < 4; ++s)
      d += pml[(size_t)s * RN + (size_t)b * NTOK + n0 + tid].y;
    invl[tid] = 1.0f / d;
  }
  f32x4 acc[4][4] = {};
  const u16* Ab = wp + (size_t)c0 * CDIM;
  for (int kcs = 0; kcs < 256; kcs += 64) {
    __syncthreads();
#pragma unroll
    for (int i = 0; i < 4; ++i) {
      int cid = i * 256 + tid;
      int row = cid >> 3, cc = cid & 7;
      *(uint4*)&Al[row][cc * 8] = *(const uint4*)(Ab + (size_t)row * CDIM + kcs + cc * 8);
      // B: sum 4 bf16 splits of pacc, scale by 1/l, back to bf16
      size_t off = ((size_t)b * NTOK + n0 + row) * CDIM + kcs + cc * 8;
      float v[8] = {0, 0, 0, 0, 0, 0, 0, 0};
#pragma unroll
      for (int s = 0; s < 4; ++s) {
        uint4 u = *(const uint4*)(pacc + (size_t)s * RN * CDIM + off);
        const u16* pu = (const u16*)&u;
#pragma unroll
        for (int j = 0; j < 8; ++j) v[j] += bf2f(pu[j]);
      }
      float iv = invl[row];
      ushort4 o0, o1;
      o0.x = f2bf(v[0] * iv); o0.y = f2bf(v[1] * iv); o0.z = f2bf(v[2] * iv); o0.w = f2bf(v[3] * iv);
      o1.x = f2bf(v[4] * iv); o1.y = f2bf(v[5] * iv); o1.z = f2bf(v[6] * iv); o1.w = f2bf(v[7] * iv);
      *(ushort4*)&Bl[row][cc * 8]     = o0;
      *(ushort4*)&Bl[row][cc * 8 + 4] = o1;
    }
    __syncthreads();
#pragma unroll
    for (int kk = 0; kk < 2; ++kk) {
      bf16x8 af[4], bfr[4];
#pragma unroll
      for (int mi = 0; mi < 4; ++mi) af[mi]  = *(const bf16x8*)&Al[wm * 64 + mi * 16 + lo][kk * 32 + hi * 8];
#pragma unroll
      for (int ni = 0; ni < 4; ++ni) bfr[ni] = *(const bf16x8*)&Bl[wn * 64 + ni * 16 + lo][kk * 32 + hi * 8];
#pragma unroll
      for (int mi = 0; mi < 4; ++mi)
#pragma unroll
        for (int ni = 0; ni < 4; ++ni)
          acc[mi][ni] = __builtin_amdgcn_mfma_f32_16x16x32_bf16(af[mi], bfr[ni], acc[mi][ni], 0, 0, 0);
    }
  }
#pragma unroll
  for (int mi = 0; mi < 4; ++mi) {
    int cbase = c0 + wm * 64 + mi * 16 + hi * 4;
#pragma unroll
    for (int r = 0; r < 4; ++r) {
      float bias = bproj[cbase + r];
#pragma unroll
      for (int ni = 0; ni < 4; ++ni) {
        int n = n0 + wn * 64 + ni * 16 + lo;
        out[((size_t)b * CDIM + cbase + r) * NTOK + n] = acc[mi][ni][r] + bias;
      }
    }
  }
}

extern "C" void kernel_launch(void* const* d_in, const int* in_sizes, int n_in,
                              void* d_out, int out_size, void* d_ws, size_t ws_size,
                              hipStream_t stream) {
  const float* x     = (const float*)d_in[0];
  const int*   fg    = (const int*)d_in[1];
  const float* Wqkv  = (const float*)d_in[2];
  const float* Wproj = (const float*)d_in[3];
  const float* bproj = (const float*)d_in[4];
  float* out = (float*)d_out;
  char* ws = (char*)d_ws;
  u16*   Qm   = (u16*)(ws);                    // 8388608
  u16*   Km   = (u16*)(ws + 8388608);          // 8388608
  u16*   Vt   = (u16*)(ws + 16777216);         // 4*272*4096*2 = 8912896
  u16*   wq   = (u16*)(ws + 25690112);         // 393216
  u16*   wp   = (u16*)(ws + 26083328);         // 131072
  u16*   pacc = (u16*)(ws + 26214400);         // 4 x 8 MiB bf16 = 33554432
  float2* pml = (float2*)(ws + 59768832);      // 512 KiB -> ends 60293120

  k_prep<<<1088, 256, 0, stream>>>(Wqkv, Wproj, fg, wq, wp, Vt);
  k_qkv<<<dim3(32, 6, 4), 256, 0, stream>>>(x, wq, fg, Qm, Km, Vt);
  k_attn<<<512, 256, 0, stream>>>(Qm, Km, Vt, pacc, pml);
  k_proj<<<dim3(32, 2, 4), 256, 0, stream>>>(pacc, pml, wp, bproj, out);
}

// Round 10
// 189.329 us; speedup vs baseline: 1.4664x; 1.4664x over previous
//
#include <hip/hip_runtime.h>
#include <hip/hip_bf16.h>

#define BATCH 4
#define CDIM  256
#define NTOK  4096
#define THREE (3*CDIM)
#define VROWS 272   // 256 V channels + 16 (fg column + 15 zero pad)

typedef unsigned short u16;
typedef __attribute__((ext_vector_type(4))) float f32x4;
typedef __attribute__((ext_vector_type(8))) short bf16x8;

#define AS1 __attribute__((address_space(1)))
#define AS3 __attribute__((address_space(3)))

__device__ __forceinline__ u16 f2bf(float x) {
  unsigned int u = __float_as_uint(x);
  unsigned int r = (u + 0x7fffu + ((u >> 16) & 1u)) >> 16;   // RTNE
  return (u16)r;
}
__device__ __forceinline__ float bf2f(u16 v) {
  return __uint_as_float(((unsigned int)v) << 16);
}

__device__ __forceinline__ void gload_lds16(const u16* g, u16* l) {
  __builtin_amdgcn_global_load_lds((AS1 const void*)g, (AS3 void*)l, 16, 0, 0);
}

// ---------------- K1: weights -> bf16; V fg/zero pad rows ----------------
__global__ void k_prep(const float* __restrict__ Wqkv, const float* __restrict__ Wproj,
                       const int* __restrict__ fg,
                       u16* __restrict__ wq, u16* __restrict__ wp,
                       u16* __restrict__ Vt) {
  int i = blockIdx.x * 256 + threadIdx.x;
  const int nq = THREE * CDIM;          // 196608
  const int np = CDIM * CDIM;           // 65536
  const int nf = BATCH * NTOK;          // 16384 (fg row c=256)
  const int nz = BATCH * 15 * NTOK;     // 245760 (zero rows c=257..271)
  if (i < nq) { wq[i] = f2bf(Wqkv[i]); return; }
  int j = i - nq;
  if (j < np) { wp[j] = f2bf(Wproj[j]); return; }
  int k = j - np;
  if (k < nf) {
    int b = k >> 12, key = k & (NTOK - 1);
    Vt[((size_t)b * VROWS + 256) * NTOK + key] = fg[k] ? 0x3F80 : 0;  // bf16 1.0/0.0
    return;
  }
  int m = k - nf;
  if (m < nz) {
    int b = m / (15 * NTOK);
    int rem = m - b * 15 * NTOK;
    int c = 257 + (rem >> 12), key = rem & (NTOK - 1);
    Vt[((size_t)b * VROWS + c) * NTOK + key] = 0;
  }
}

// ---------------- K2: x [B][C][N] f32 -> xbf [B][N][C] bf16 ----------------
__global__ __launch_bounds__(256) void k_transpose(const float* __restrict__ x, u16* __restrict__ xbf) {
  __shared__ u16 t[64][65];
  int n0 = blockIdx.x * 64;
  int c0 = blockIdx.y * 64;
  int b  = blockIdx.z;
  int tid = threadIdx.x;
  const float* xp = x + (size_t)b * CDIM * NTOK;
  int nl = tid & 63;
  int cb = tid >> 6;
#pragma unroll
  for (int i = 0; i < 16; ++i) {
    int cl = cb * 16 + i;
    t[nl][cl] = f2bf(xp[(size_t)(c0 + cl) * NTOK + n0 + nl]);
  }
  __syncthreads();
  int cl = tid & 63;
  int nb = tid >> 6;
  u16* op = xbf + ((size_t)b * NTOK + n0) * CDIM + c0;
#pragma unroll
  for (int i = 0; i < 16; ++i) {
    int nl2 = nb * 16 + i;
    op[(size_t)nl2 * CDIM + cl] = t[nl2][cl];
  }
}

// ---------------- K3: qkv GEMM. Q (x log2e/16), K row-major; V^T [c][key], fg-zeroed ----------------
__global__ __launch_bounds__(256) void k_qkv(const u16* __restrict__ xbf, const u16* __restrict__ wq,
                                             const int* __restrict__ fg,
                                             u16* __restrict__ Qm, u16* __restrict__ Km,
                                             u16* __restrict__ Vt) {
  __shared__ u16 Al[128][72];
  __shared__ u16 Bl[128][72];
  int n0 = blockIdx.x * 128;
  int d0 = blockIdx.y * 128;
  int b  = blockIdx.z;
  int tid = threadIdx.x;
  int lane = tid & 63, w = tid >> 6;
  int lo = lane & 15, hi = lane >> 4;
  int wm = w >> 1, wn = w & 1;
  f32x4 acc[4][4] = {};
  const u16* Ab = xbf + ((size_t)b * NTOK + n0) * CDIM;
  const u16* Bb = wq + (size_t)d0 * CDIM;
  for (int kc = 0; kc < 256; kc += 64) {
    __syncthreads();
#pragma unroll
    for (int i = 0; i < 4; ++i) {
      int cid = i * 256 + tid;
      int row = cid >> 3, cc = cid & 7;
      *(uint4*)&Al[row][cc * 8] = *(const uint4*)(Ab + (size_t)row * CDIM + kc + cc * 8);
      *(uint4*)&Bl[row][cc * 8] = *(const uint4*)(Bb + (size_t)row * CDIM + kc + cc * 8);
    }
    __syncthreads();
#pragma unroll
    for (int kk = 0; kk < 2; ++kk) {
      bf16x8 af[4], bfr[4];
#pragma unroll
      for (int mi = 0; mi < 4; ++mi) af[mi]  = *(const bf16x8*)&Al[wm * 64 + mi * 16 + lo][kk * 32 + hi * 8];
#pragma unroll
      for (int ni = 0; ni < 4; ++ni) bfr[ni] = *(const bf16x8*)&Bl[wn * 64 + ni * 16 + lo][kk * 32 + hi * 8];
#pragma unroll
      for (int mi = 0; mi < 4; ++mi)
#pragma unroll
        for (int ni = 0; ni < 4; ++ni)
          acc[mi][ni] = __builtin_amdgcn_mfma_f32_16x16x32_bf16(af[mi], bfr[ni], acc[mi][ni], 0, 0, 0);
    }
  }
  int seg = d0 >> 8;   // 0=Q 1=K 2=V
  const float QSC = 0.0625f * 1.4426950408889634f;   // (1/sqrt(C)) * log2(e)
#pragma unroll
  for (int mi = 0; mi < 4; ++mi) {
    int nbase = n0 + wm * 64 + mi * 16 + hi * 4;
#pragma unroll
    for (int ni = 0; ni < 4; ++ni) {
      int d = d0 + wn * 64 + ni * 16 + lo;
      if (seg == 0) {
#pragma unroll
        for (int r = 0; r < 4; ++r)
          Qm[((size_t)b * NTOK + nbase + r) * CDIM + d] = f2bf(acc[mi][ni][r] * QSC);
      } else if (seg == 1) {
        int dk = d - 256;
#pragma unroll
        for (int r = 0; r < 4; ++r)
          Km[((size_t)b * NTOK + nbase + r) * CDIM + dk] = f2bf(acc[mi][ni][r]);
      } else {
        int dv = d - 512;
        ushort4 pk;
        pk.x = fg[b * NTOK + nbase + 0] ? f2bf(acc[mi][ni][0]) : (u16)0;
        pk.y = fg[b * NTOK + nbase + 1] ? f2bf(acc[mi][ni][1]) : (u16)0;
        pk.z = fg[b * NTOK + nbase + 2] ? f2bf(acc[mi][ni][2]) : (u16)0;
        pk.w = fg[b * NTOK + nbase + 3] ? f2bf(acc[mi][ni][3]) : (u16)0;
        *(ushort4*)&Vt[((size_t)b * VROWS + dv) * NTOK + nbase] = pk;
      }
    }
  }
}

// ---------------- K4: flash attention (R6 verbatim — measured 135.5 us) ----------------
// grid = 128*nsplit blocks; 4 waves x 32 q-rows; KBLK=32; double-buffered staging.
// P = exp2(QK - 12); masked keys carry garbage P but V rows are zeroed; l comes from
// V's fg column (c=256) inside the PV MFMA. No per-iter mask loads / reductions.
__global__ __launch_bounds__(256, 2) void k_attn(const u16* __restrict__ Qm, const u16* __restrict__ Km,
                                                 const u16* __restrict__ Vt,
                                                 u16* __restrict__ pacc, float2* __restrict__ pml,
                                                 int lsplit) {
  __shared__ u16 Kl[2][32 * 256];    // 16KB x2; row=512B, 16B-chunk ^= (row&7)<<4
  __shared__ u16 Vl[2][VROWS * 32];  // 17KB x2; row=64B (V^T [c][key]), chunk ^= row&3
  __shared__ u16 Pl[4][32 * 32];     // 2KB/wave; row=64B (P [q][key]), chunk ^= q&3
  const float FM = 12.0f;            // fixed softmax max (log2 units), folded into sv init
  int nwg = gridDim.x;
  int cpx = nwg >> 3;
  int orig = blockIdx.x;
  int wg = (orig & 7) * cpx + (orig >> 3);   // bijective XCD swizzle (nwg % 8 == 0)
  int qt = wg & 31;
  int bs = wg >> 5;
  int s_k = bs & ((1 << lsplit) - 1);
  int b   = bs >> lsplit;
  int chunk = NTOK >> lsplit;
  int koff  = s_k * chunk;
  int iters = chunk >> 5;

  int tid = threadIdx.x;
  int lane = tid & 63, w = tid >> 6;
  int lo = lane & 15, hi = lane >> 4;
  int n0 = qt * 128 + w * 32;
  // Q: 32 rows x 256 in registers (64 VGPR)
  bf16x8 qf[2][8];
#pragma unroll
  for (int s = 0; s < 2; ++s) {
    const u16* qp = Qm + ((size_t)b * NTOK + n0 + s * 16 + lo) * CDIM + hi * 8;
#pragma unroll
    for (int ks = 0; ks < 8; ++ks) qf[s][ks] = *(const bf16x8*)(qp + ks * 32);
  }
  f32x4 acc[2][17] = {};   // [s][cf]; cf=16 is the l column (V fg column)
  const u16* kbase = Km + (size_t)b * NTOK * CDIM;
  const u16* vbase = Vt + (size_t)b * VROWS * NTOK;
  int kc  = lane & 31;   // K staging: 16B chunk within row pair
  int krp = lane >> 5;
  int vr  = lane >> 2;   // V staging: row within 16-row group
  int vc  = lane & 3;

  // stage K (16 insts) and V (17 insts: 272 rows) for key-block m0 into buffer buf
  auto stage = [&](int buf, int m0) {
    u16* kld = &Kl[buf][w * 2048];
#pragma unroll
    for (int j = 0; j < 4; ++j) {
      int row = w * 8 + j * 2 + krp;
      int sb = (kc * 16) ^ ((row & 7) << 4);
      gload_lds16(kbase + (size_t)(m0 + row) * CDIM + (sb >> 1), kld + j * 512);
    }
#pragma unroll
    for (int j = 0; j < 4; ++j) {
      int idx = j * 4 + w;                 // 0..15
      int r = idx * 16 + vr;
      int d = vc ^ (r & 3);
      gload_lds16(vbase + (size_t)r * NTOK + m0 + d * 8, &Vl[buf][idx * 512]);
    }
    if (w == 0) {                          // 17th: fg + zero rows (256..271)
      int r = 256 + vr;
      int d = vc ^ (r & 3);
      gload_lds16(vbase + (size_t)r * NTOK + m0 + d * 8, &Vl[buf][16 * 512]);
    }
  };

  stage(0, koff);
  __syncthreads();   // implicit vmcnt(0) drain covers the gload_lds deposits
  for (int it = 0; it < iters; ++it) {
    int cur = it & 1;
    int m0 = koff + it * 32;
    if (it + 1 < iters) stage(cur ^ 1, m0 + 32);   // prefetch next tile
    // S - FM = Q K^T - 12 (log2 domain): fold -FM into the accumulator init
    f32x4 sv[2][2];
#pragma unroll
    for (int s = 0; s < 2; ++s)
#pragma unroll
      for (int ni = 0; ni < 2; ++ni)
#pragma unroll
        for (int r = 0; r < 4; ++r) sv[s][ni][r] = -FM;
    __builtin_amdgcn_s_setprio(1);
#pragma unroll
    for (int ks = 0; ks < 8; ++ks) {
      bf16x8 kf[2];
#pragma unroll
      for (int ni = 0; ni < 2; ++ni) {
        int row = ni * 16 + lo;
        const char* kp = (const char*)&Kl[cur][0] + row * 512 + ((ks * 64 + hi * 16) ^ ((row & 7) << 4));
        kf[ni] = *(const bf16x8*)kp;
      }
#pragma unroll
      for (int s = 0; s < 2; ++s)
#pragma unroll
        for (int ni = 0; ni < 2; ++ni)
          sv[s][ni] = __builtin_amdgcn_mfma_f32_16x16x32_bf16(qf[s][ks], kf[ni], sv[s][ni], 0, 0, 0);
    }
    __builtin_amdgcn_s_setprio(0);
    // P = exp2(S - FM); straight to bf16, no mask work (mask lives in V)
#pragma unroll
    for (int s = 0; s < 2; ++s)
#pragma unroll
      for (int ni = 0; ni < 2; ++ni)
#pragma unroll
        for (int r = 0; r < 4; ++r) {
          int q = s * 16 + hi * 4 + r;
          int byteoff = q * 64 + ((((ni * 16 + lo) * 2)) ^ ((q & 3) << 4));
          *(u16*)((char*)&Pl[w][0] + byteoff) = f2bf(exp2f(sv[s][ni][r]));
        }
    // PV: A from Pl, B from Vl; cf=16 accumulates l via the fg column
    bf16x8 pa[2];
#pragma unroll
    for (int s = 0; s < 2; ++s) {
      const char* pp = (const char*)&Pl[w][0] + (s * 16 + lo) * 64 + ((hi ^ (lo & 3)) << 4);
      pa[s] = *(const bf16x8*)pp;
    }
    __builtin_amdgcn_s_setprio(1);
#pragma unroll
    for (int cf = 0; cf < 17; ++cf) {
      const char* vp = (const char*)&Vl[cur][0] + (cf * 16 + lo) * 64 + ((hi ^ (lo & 3)) << 4);
      bf16x8 vb = *(const bf16x8*)vp;
#pragma unroll
      for (int s = 0; s < 2; ++s)
        acc[s][cf] = __builtin_amdgcn_mfma_f32_16x16x32_bf16(pa[s], vb, acc[s][cf], 0, 0, 0);
    }
    __builtin_amdgcn_s_setprio(0);
    __syncthreads();   // drains next-tile stage loads + all waves done with buf[cur]
  }
  // epilogue: bf16 unnormalized partials + (m=FM, l) per row
  u16* pb = pacc + (((size_t)s_k * BATCH + b) * NTOK + n0) * CDIM;
  float2* pm = pml + ((size_t)s_k * BATCH + b) * NTOK + n0;
#pragma unroll
  for (int s = 0; s < 2; ++s)
#pragma unroll
    for (int r = 0; r < 4; ++r) {
      int row = s * 16 + hi * 4 + r;
#pragma unroll
      for (int cf = 0; cf < 16; ++cf)
        pb[(size_t)row * CDIM + cf * 16 + lo] = f2bf(acc[s][cf][r]);
      if (lo == 0) {
        float2 v; v.x = FM; v.y = acc[s][16][r];
        pm[row] = v;
      }
    }
}

// ---------------- K5: fused combine + projection ----------------
// out[b][c][n] = b_proj[c] + sum_k h[b][n][k] Wp[c][k],  h = (sum_s pacc_s) / (sum_s l_s)
// (all split maxima equal FM -> combine weights are uniform 1/sum(l)).
__global__ __launch_bounds__(256) void k_proj(const u16* __restrict__ pacc,
                                              const float2* __restrict__ pml,
                                              const u16* __restrict__ wp,
                                              const float* __restrict__ bproj, float* __restrict__ out) {
  __shared__ u16 Al[128][72];
  __shared__ u16 Bl[128][72];
  __shared__ float invl[128];
  const int RN = BATCH * NTOK;
  int n0 = blockIdx.x * 128;
  int c0 = blockIdx.y * 128;
  int b  = blockIdx.z;
  int tid = threadIdx.x;
  int lane = tid & 63, w = tid >> 6;
  int lo = lane & 15, hi = lane >> 4;
  int wm = w >> 1, wn = w & 1;
  if (tid < 128) {
    float d = 0.0f;
#pragma unroll
    for (int s = 0; s < 4; ++s)
      d += pml[(size_t)s * RN + (size_t)b * NTOK + n0 + tid].y;
    invl[tid] = 1.0f / d;
  }
  f32x4 acc[4][4] = {};
  const u16* Ab = wp + (size_t)c0 * CDIM;
  for (int kcs = 0; kcs < 256; kcs += 64) {
    __syncthreads();
#pragma unroll
    for (int i = 0; i < 4; ++i) {
      int cid = i * 256 + tid;
      int row = cid >> 3, cc = cid & 7;
      *(uint4*)&Al[row][cc * 8] = *(const uint4*)(Ab + (size_t)row * CDIM + kcs + cc * 8);
      // B: sum 4 bf16 splits of pacc, scale by 1/l, back to bf16
      size_t off = ((size_t)b * NTOK + n0 + row) * CDIM + kcs + cc * 8;
      float v[8] = {0, 0, 0, 0, 0, 0, 0, 0};
#pragma unroll
      for (int s = 0; s < 4; ++s) {
        uint4 u = *(const uint4*)(pacc + (size_t)s * RN * CDIM + off);
        const u16* pu = (const u16*)&u;
#pragma unroll
        for (int j = 0; j < 8; ++j) v[j] += bf2f(pu[j]);
      }
      float iv = invl[row];
      ushort4 o0, o1;
      o0.x = f2bf(v[0] * iv); o0.y = f2bf(v[1] * iv); o0.z = f2bf(v[2] * iv); o0.w = f2bf(v[3] * iv);
      o1.x = f2bf(v[4] * iv); o1.y = f2bf(v[5] * iv); o1.z = f2bf(v[6] * iv); o1.w = f2bf(v[7] * iv);
      *(ushort4*)&Bl[row][cc * 8]     = o0;
      *(ushort4*)&Bl[row][cc * 8 + 4] = o1;
    }
    __syncthreads();
#pragma unroll
    for (int kk = 0; kk < 2; ++kk) {
      bf16x8 af[4], bfr[4];
#pragma unroll
      for (int mi = 0; mi < 4; ++mi) af[mi]  = *(const bf16x8*)&Al[wm * 64 + mi * 16 + lo][kk * 32 + hi * 8];
#pragma unroll
      for (int ni = 0; ni < 4; ++ni) bfr[ni] = *(const bf16x8*)&Bl[wn * 64 + ni * 16 + lo][kk * 32 + hi * 8];
#pragma unroll
      for (int mi = 0; mi < 4; ++mi)
#pragma unroll
        for (int ni = 0; ni < 4; ++ni)
          acc[mi][ni] = __builtin_amdgcn_mfma_f32_16x16x32_bf16(af[mi], bfr[ni], acc[mi][ni], 0, 0, 0);
    }
  }
#pragma unroll
  for (int mi = 0; mi < 4; ++mi) {
    int cbase = c0 + wm * 64 + mi * 16 + hi * 4;
#pragma unroll
    for (int r = 0; r < 4; ++r) {
      float bias = bproj[cbase + r];
#pragma unroll
      for (int ni = 0; ni < 4; ++ni) {
        int n = n0 + wn * 64 + ni * 16 + lo;
        out[((size_t)b * CDIM + cbase + r) * NTOK + n] = acc[mi][ni][r] + bias;
      }
    }
  }
}

extern "C" void kernel_launch(void* const* d_in, const int* in_sizes, int n_in,
                              void* d_out, int out_size, void* d_ws, size_t ws_size,
                              hipStream_t stream) {
  const float* x     = (const float*)d_in[0];
  const int*   fg    = (const int*)d_in[1];
  const float* Wqkv  = (const float*)d_in[2];
  const float* Wproj = (const float*)d_in[3];
  const float* bproj = (const float*)d_in[4];
  float* out = (float*)d_out;
  char* ws = (char*)d_ws;
  u16*   xbf  = (u16*)(ws);                    // 8388608 B
  u16*   Qm   = (u16*)(ws + 8388608);          // 8388608
  u16*   Km   = (u16*)(ws + 16777216);         // 8388608
  u16*   Vt   = (u16*)(ws + 25165824);         // 4*272*4096*2 = 8912896
  u16*   wq   = (u16*)(ws + 34078720);         // 393216
  u16*   wp   = (u16*)(ws + 34471936);         // 131072  -> ends 34603008
  u16*   pacc = (u16*)(ws + 34603008);         // 4 x 8 MiB bf16 = 33554432
  float2* pml = (float2*)(ws + 68157440);      // 512 KiB -> ends 68681728

  k_prep<<<2048, 256, 0, stream>>>(Wqkv, Wproj, fg, wq, wp, Vt);
  k_transpose<<<dim3(64, 4, 4), 256, 0, stream>>>(x, xbf);
  k_qkv<<<dim3(32, 6, 4), 256, 0, stream>>>(xbf, wq, fg, Qm, Km, Vt);
  k_attn<<<512, 256, 0, stream>>>(Qm, Km, Vt, pacc, pml, 2);
  k_proj<<<dim3(32, 2, 4), 256, 0, stream>>>(pacc, pml, wp, bproj, out);
}

// Round 11
// 187.195 us; speedup vs baseline: 1.4831x; 1.0114x over previous
//
#include <hip/hip_runtime.h>
#include <hip/hip_bf16.h>

#define BATCH 4
#define CDIM  256
#define NTOK  4096
#define THREE (3*CDIM)
#define VROWS 272   // 256 V channels + fg row at 256 (257..271 unused)

typedef unsigned short u16;
typedef __attribute__((ext_vector_type(4))) float f32x4;
typedef __attribute__((ext_vector_type(8))) short bf16x8;

#define AS1 __attribute__((address_space(1)))
#define AS3 __attribute__((address_space(3)))

__device__ __forceinline__ u16 f2bf(float x) {
  unsigned int u = __float_as_uint(x);
  unsigned int r = (u + 0x7fffu + ((u >> 16) & 1u)) >> 16;   // RTNE
  return (u16)r;
}
__device__ __forceinline__ float bf2f(u16 v) {
  return __uint_as_float(((unsigned int)v) << 16);
}

__device__ __forceinline__ void gload_lds16(const u16* g, u16* l) {
  __builtin_amdgcn_global_load_lds((AS1 const void*)g, (AS3 void*)l, 16, 0, 0);
}

// ---------------- K1: weights -> bf16; fg -> bf16 row in Vt ----------------
__global__ void k_prep(const float* __restrict__ Wqkv, const float* __restrict__ Wproj,
                       const int* __restrict__ fg,
                       u16* __restrict__ wq, u16* __restrict__ wp,
                       u16* __restrict__ Vt) {
  int i = blockIdx.x * 256 + threadIdx.x;
  const int nq = THREE * CDIM;          // 196608
  const int np = CDIM * CDIM;           // 65536
  const int nf = BATCH * NTOK;          // 16384 (fg row c=256)
  if (i < nq) { wq[i] = f2bf(Wqkv[i]); return; }
  int j = i - nq;
  if (j < np) { wp[j] = f2bf(Wproj[j]); return; }
  int k = j - np;
  if (k < nf) {
    int b = k >> 12, key = k & (NTOK - 1);
    Vt[((size_t)b * VROWS + 256) * NTOK + key] = fg[k] ? 0x3F80 : 0;  // bf16 1.0/0.0
  }
}

// ---------------- K2: x [B][C][N] f32 -> xbf [B][N][C] bf16 ----------------
__global__ __launch_bounds__(256) void k_transpose(const float* __restrict__ x, u16* __restrict__ xbf) {
  __shared__ u16 t[64][65];
  int n0 = blockIdx.x * 64;
  int c0 = blockIdx.y * 64;
  int b  = blockIdx.z;
  int tid = threadIdx.x;
  const float* xp = x + (size_t)b * CDIM * NTOK;
  int nl = tid & 63;
  int cb = tid >> 6;
#pragma unroll
  for (int i = 0; i < 16; ++i) {
    int cl = cb * 16 + i;
    t[nl][cl] = f2bf(xp[(size_t)(c0 + cl) * NTOK + n0 + nl]);
  }
  __syncthreads();
  int cl = tid & 63;
  int nb = tid >> 6;
  u16* op = xbf + ((size_t)b * NTOK + n0) * CDIM + c0;
#pragma unroll
  for (int i = 0; i < 16; ++i) {
    int nl2 = nb * 16 + i;
    op[(size_t)nl2 * CDIM + cl] = t[nl2][cl];
  }
}

// ---------------- K3: qkv GEMM. Q (x log2e/16), K row-major; V^T [c][key], fg-zeroed ----------------
__global__ __launch_bounds__(256) void k_qkv(const u16* __restrict__ xbf, const u16* __restrict__ wq,
                                             const int* __restrict__ fg,
                                             u16* __restrict__ Qm, u16* __restrict__ Km,
                                             u16* __restrict__ Vt) {
  __shared__ u16 Al[128][72];
  __shared__ u16 Bl[128][72];
  int n0 = blockIdx.x * 128;
  int d0 = blockIdx.y * 128;
  int b  = blockIdx.z;
  int tid = threadIdx.x;
  int lane = tid & 63, w = tid >> 6;
  int lo = lane & 15, hi = lane >> 4;
  int wm = w >> 1, wn = w & 1;
  f32x4 acc[4][4] = {};
  const u16* Ab = xbf + ((size_t)b * NTOK + n0) * CDIM;
  const u16* Bb = wq + (size_t)d0 * CDIM;
  for (int kc = 0; kc < 256; kc += 64) {
    __syncthreads();
#pragma unroll
    for (int i = 0; i < 4; ++i) {
      int cid = i * 256 + tid;
      int row = cid >> 3, cc = cid & 7;
      *(uint4*)&Al[row][cc * 8] = *(const uint4*)(Ab + (size_t)row * CDIM + kc + cc * 8);
      *(uint4*)&Bl[row][cc * 8] = *(const uint4*)(Bb + (size_t)row * CDIM + kc + cc * 8);
    }
    __syncthreads();
#pragma unroll
    for (int kk = 0; kk < 2; ++kk) {
      bf16x8 af[4], bfr[4];
#pragma unroll
      for (int mi = 0; mi < 4; ++mi) af[mi]  = *(const bf16x8*)&Al[wm * 64 + mi * 16 + lo][kk * 32 + hi * 8];
#pragma unroll
      for (int ni = 0; ni < 4; ++ni) bfr[ni] = *(const bf16x8*)&Bl[wn * 64 + ni * 16 + lo][kk * 32 + hi * 8];
#pragma unroll
      for (int mi = 0; mi < 4; ++mi)
#pragma unroll
        for (int ni = 0; ni < 4; ++ni)
          acc[mi][ni] = __builtin_amdgcn_mfma_f32_16x16x32_bf16(af[mi], bfr[ni], acc[mi][ni], 0, 0, 0);
    }
  }
  int seg = d0 >> 8;   // 0=Q 1=K 2=V
  const float QSC = 0.0625f * 1.4426950408889634f;   // (1/sqrt(C)) * log2(e)
#pragma unroll
  for (int mi = 0; mi < 4; ++mi) {
    int nbase = n0 + wm * 64 + mi * 16 + hi * 4;
#pragma unroll
    for (int ni = 0; ni < 4; ++ni) {
      int d = d0 + wn * 64 + ni * 16 + lo;
      if (seg == 0) {
#pragma unroll
        for (int r = 0; r < 4; ++r)
          Qm[((size_t)b * NTOK + nbase + r) * CDIM + d] = f2bf(acc[mi][ni][r] * QSC);
      } else if (seg == 1) {
        int dk = d - 256;
#pragma unroll
        for (int r = 0; r < 4; ++r)
          Km[((size_t)b * NTOK + nbase + r) * CDIM + dk] = f2bf(acc[mi][ni][r]);
      } else {
        int dv = d - 512;
        ushort4 pk;
        pk.x = fg[b * NTOK + nbase + 0] ? f2bf(acc[mi][ni][0]) : (u16)0;
        pk.y = fg[b * NTOK + nbase + 1] ? f2bf(acc[mi][ni][1]) : (u16)0;
        pk.z = fg[b * NTOK + nbase + 2] ? f2bf(acc[mi][ni][2]) : (u16)0;
        pk.w = fg[b * NTOK + nbase + 3] ? f2bf(acc[mi][ni][3]) : (u16)0;
        *(ushort4*)&Vt[((size_t)b * VROWS + dv) * NTOK + nbase] = pk;
      }
    }
  }
}

// ---------------- K4: flash attention (R10 base + 3 deltas) ----------------
// grid = 512 blocks; 4 waves x 32 q-rows; KBLK=32; double-buffered staging.
// Deltas vs R10 (134.9 us): (1) l in VALU via fgl (acc 136->128 AGPR, fits the
// 256-reg/2-wave tier); (2) Pl chunk-XOR swizzle (chunk' = chunk ^ hi) kills the
// 8-way P-write conflict; (3) V tile-17 staging + cf=16 MFMAs dropped.
__global__ __launch_bounds__(256, 2) void k_attn(const u16* __restrict__ Qm, const u16* __restrict__ Km,
                                                 const u16* __restrict__ Vt,
                                                 u16* __restrict__ pacc, float2* __restrict__ pml,
                                                 int lsplit) {
  __shared__ u16 Kl[2][32 * 256];    // 16KB x2; row=512B, 16B-chunk ^= (row&7)<<4
  __shared__ u16 Vl[2][256 * 32];    // 16KB x2; row=64B (V^T [c][key]), chunk ^= row&3
  __shared__ u16 Pl[4][32 * 32];     // 2KB/wave; row=64B, 16B-chunk ^= writer-hi (q>>2&3)
  __shared__ u16 fgl[1024];          // bf16 fg for this chunk's 1024 keys
  const float FM = 12.0f;            // fixed softmax max (log2 units), folded into sv init
  int nwg = gridDim.x;
  int cpx = nwg >> 3;
  int orig = blockIdx.x;
  int wg = (orig & 7) * cpx + (orig >> 3);   // bijective XCD swizzle (nwg % 8 == 0)
  int qt = wg & 31;
  int bs = wg >> 5;
  int s_k = bs & ((1 << lsplit) - 1);
  int b   = bs >> lsplit;
  int chunk = NTOK >> lsplit;
  int koff  = s_k * chunk;
  int iters = chunk >> 5;

  int tid = threadIdx.x;
  int lane = tid & 63, w = tid >> 6;
  int lo = lane & 15, hi = lane >> 4;
  int n0 = qt * 128 + w * 32;
  // Q: 32 rows x 256 in registers (64 VGPR)
  bf16x8 qf[2][8];
#pragma unroll
  for (int s = 0; s < 2; ++s) {
    const u16* qp = Qm + ((size_t)b * NTOK + n0 + s * 16 + lo) * CDIM + hi * 8;
#pragma unroll
    for (int ks = 0; ks < 8; ++ks) qf[s][ks] = *(const bf16x8*)(qp + ks * 32);
  }
  f32x4 acc[2][16] = {};
  float lsum[2][4] = {};
  const u16* kbase = Km + (size_t)b * NTOK * CDIM;
  const u16* vbase = Vt + (size_t)b * VROWS * NTOK;
  const u16* fgrow = vbase + (size_t)256 * NTOK;   // bf16 fg row
  int kc  = lane & 31;   // K staging: 16B chunk within row pair
  int krp = lane >> 5;
  int vr  = lane >> 2;   // V staging: row within 16-row group
  int vc  = lane & 3;

  // stage K (4 insts/wave) and V (4 insts/wave) for key-block m0 into buffer buf
  auto stage = [&](int buf, int m0) {
    u16* kld = &Kl[buf][w * 2048];
#pragma unroll
    for (int j = 0; j < 4; ++j) {
      int row = w * 8 + j * 2 + krp;
      int sb = (kc * 16) ^ ((row & 7) << 4);
      gload_lds16(kbase + (size_t)(m0 + row) * CDIM + (sb >> 1), kld + j * 512);
    }
#pragma unroll
    for (int j = 0; j < 4; ++j) {
      int idx = j * 4 + w;                 // 0..15
      int r = idx * 16 + vr;
      int d = vc ^ (r & 3);
      gload_lds16(vbase + (size_t)r * NTOK + m0 + d * 8, &Vl[buf][idx * 512]);
    }
  };

  // prologue: fg chunk (waves 0,1) + tile 0; barrier drains all gload_lds
  if (w < 2) gload_lds16(fgrow + koff + w * 512 + lane * 8, &fgl[w * 512 + lane * 8]);
  stage(0, koff);
  __syncthreads();
  for (int it = 0; it < iters; ++it) {
    int cur = it & 1;
    int m0 = koff + it * 32;
    if (it + 1 < iters) stage(cur ^ 1, m0 + 32);   // prefetch next tile
    // S - FM = Q K^T - 12 (log2 domain): fold -FM into the accumulator init
    f32x4 sv[2][2];
#pragma unroll
    for (int s = 0; s < 2; ++s)
#pragma unroll
      for (int ni = 0; ni < 2; ++ni)
#pragma unroll
        for (int r = 0; r < 4; ++r) sv[s][ni][r] = -FM;
    __builtin_amdgcn_s_setprio(1);
#pragma unroll
    for (int ks = 0; ks < 8; ++ks) {
      bf16x8 kf[2];
#pragma unroll
      for (int ni = 0; ni < 2; ++ni) {
        int row = ni * 16 + lo;
        const char* kp = (const char*)&Kl[cur][0] + row * 512 + ((ks * 64 + hi * 16) ^ ((row & 7) << 4));
        kf[ni] = *(const bf16x8*)kp;
      }
#pragma unroll
      for (int s = 0; s < 2; ++s)
#pragma unroll
        for (int ni = 0; ni < 2; ++ni)
          sv[s][ni] = __builtin_amdgcn_mfma_f32_16x16x32_bf16(qf[s][ks], kf[ni], sv[s][ni], 0, 0, 0);
    }
    __builtin_amdgcn_s_setprio(0);
    // P = exp2(S - FM); l += P*fg (fg from LDS); P -> bf16 -> swizzled Pl
    float fgm[2];
    fgm[0] = bf2f(fgl[it * 32 + lo]);
    fgm[1] = bf2f(fgl[it * 32 + 16 + lo]);
#pragma unroll
    for (int s = 0; s < 2; ++s)
#pragma unroll
      for (int ni = 0; ni < 2; ++ni)
#pragma unroll
        for (int r = 0; r < 4; ++r) {
          float e = exp2f(sv[s][ni][r]);
          lsum[s][r] += e * fgm[ni];
          int q = s * 16 + hi * 4 + r;
          int key = ni * 16 + lo;
          int chnk = (key >> 3) ^ hi;            // writer-hi == q>>2 & 3
          int byteoff = q * 64 + (chnk << 4) + (key & 7) * 2;
          *(u16*)((char*)&Pl[w][0] + byteoff) = f2bf(e);
        }
    // PV: A from Pl (inverse swizzle: chunk hi ^ (lo>>2)), B from Vl
    bf16x8 pa[2];
#pragma unroll
    for (int s = 0; s < 2; ++s) {
      const char* pp = (const char*)&Pl[w][0] + (s * 16 + lo) * 64 + ((hi ^ ((lo >> 2) & 3)) << 4);
      pa[s] = *(const bf16x8*)pp;
    }
    __builtin_amdgcn_s_setprio(1);
#pragma unroll
    for (int cf = 0; cf < 16; ++cf) {
      const char* vp = (const char*)&Vl[cur][0] + (cf * 16 + lo) * 64 + ((hi ^ (lo & 3)) << 4);
      bf16x8 vb = *(const bf16x8*)vp;
#pragma unroll
      for (int s = 0; s < 2; ++s)
        acc[s][cf] = __builtin_amdgcn_mfma_f32_16x16x32_bf16(pa[s], vb, acc[s][cf], 0, 0, 0);
    }
    __builtin_amdgcn_s_setprio(0);
    __syncthreads();   // drains next-tile stage loads + all waves done with buf[cur]
  }
  // one-time cross-lane l reduction (sum over the 16 lanes sharing hi)
  float ls[2][4];
#pragma unroll
  for (int s = 0; s < 2; ++s)
#pragma unroll
    for (int r = 0; r < 4; ++r) {
      float t = lsum[s][r];
      t += __shfl_xor(t, 1); t += __shfl_xor(t, 2);
      t += __shfl_xor(t, 4); t += __shfl_xor(t, 8);
      ls[s][r] = t;
    }
  // epilogue: bf16 unnormalized partials + (m=FM, l) per row
  u16* pb = pacc + (((size_t)s_k * BATCH + b) * NTOK + n0) * CDIM;
  float2* pm = pml + ((size_t)s_k * BATCH + b) * NTOK + n0;
#pragma unroll
  for (int s = 0; s < 2; ++s)
#pragma unroll
    for (int r = 0; r < 4; ++r) {
      int row = s * 16 + hi * 4 + r;
#pragma unroll
      for (int cf = 0; cf < 16; ++cf)
        pb[(size_t)row * CDIM + cf * 16 + lo] = f2bf(acc[s][cf][r]);
      if (lo == 0) {
        float2 v; v.x = FM; v.y = ls[s][r];
        pm[row] = v;
      }
    }
}

// ---------------- K5: fused combine + projection ----------------
// out[b][c][n] = b_proj[c] + sum_k h[b][n][k] Wp[c][k],  h = (sum_s pacc_s) / (sum_s l_s)
__global__ __launch_bounds__(256) void k_proj(const u16* __restrict__ pacc,
                                              const float2* __restrict__ pml,
                                              const u16* __restrict__ wp,
                                              const float* __restrict__ bproj, float* __restrict__ out) {
  __shared__ u16 Al[128][72];
  __shared__ u16 Bl[128][72];
  __shared__ float invl[128];
  const int RN = BATCH * NTOK;
  int n0 = blockIdx.x * 128;
  int c0 = blockIdx.y * 128;
  int b  = blockIdx.z;
  int tid = threadIdx.x;
  int lane = tid & 63, w = tid >> 6;
  int lo = lane & 15, hi = lane >> 4;
  int wm = w >> 1, wn = w & 1;
  if (tid < 128) {
    float d = 0.0f;
#pragma unroll
    for (int s = 0; s < 4; ++s)
      d += pml[(size_t)s * RN + (size_t)b * NTOK + n0 + tid].y;
    invl[tid] = 1.0f / d;
  }
  f32x4 acc[4][4] = {};
  const u16* Ab = wp + (size_t)c0 * CDIM;
  for (int kcs = 0; kcs < 256; kcs += 64) {
    __syncthreads();
#pragma unroll
    for (int i = 0; i < 4; ++i) {
      int cid = i * 256 + tid;
      int row = cid >> 3, cc = cid & 7;
      *(uint4*)&Al[row][cc * 8] = *(const uint4*)(Ab + (size_t)row * CDIM + kcs + cc * 8);
      // B: sum 4 bf16 splits of pacc, scale by 1/l, back to bf16
      size_t off = ((size_t)b * NTOK + n0 + row) * CDIM + kcs + cc * 8;
      float v[8] = {0, 0, 0, 0, 0, 0, 0, 0};
#pragma unroll
      for (int s = 0; s < 4; ++s) {
        uint4 u = *(const uint4*)(pacc + (size_t)s * RN * CDIM + off);
        const u16* pu = (const u16*)&u;
#pragma unroll
        for (int j = 0; j < 8; ++j) v[j] += bf2f(pu[j]);
      }
      float iv = invl[row];
      ushort4 o0, o1;
      o0.x = f2bf(v[0] * iv); o0.y = f2bf(v[1] * iv); o0.z = f2bf(v[2] * iv); o0.w = f2bf(v[3] * iv);
      o1.x = f2bf(v[4] * iv); o1.y = f2bf(v[5] * iv); o1.z = f2bf(v[6] * iv); o1.w = f2bf(v[7] * iv);
      *(ushort4*)&Bl[row][cc * 8]     = o0;
      *(ushort4*)&Bl[row][cc * 8 + 4] = o1;
    }
    __syncthreads();
#pragma unroll
    for (int kk = 0; kk < 2; ++kk) {
      bf16x8 af[4], bfr[4];
#pragma unroll
      for (int mi = 0; mi < 4; ++mi) af[mi]  = *(const bf16x8*)&Al[wm * 64 + mi * 16 + lo][kk * 32 + hi * 8];
#pragma unroll
      for (int ni = 0; ni < 4; ++ni) bfr[ni] = *(const bf16x8*)&Bl[wn * 64 + ni * 16 + lo][kk * 32 + hi * 8];
#pragma unroll
      for (int mi = 0; mi < 4; ++mi)
#pragma unroll
        for (int ni = 0; ni < 4; ++ni)
          acc[mi][ni] = __builtin_amdgcn_mfma_f32_16x16x32_bf16(af[mi], bfr[ni], acc[mi][ni], 0, 0, 0);
    }
  }
#pragma unroll
  for (int mi = 0; mi < 4; ++mi) {
    int cbase = c0 + wm * 64 + mi * 16 + hi * 4;
#pragma unroll
    for (int r = 0; r < 4; ++r) {
      float bias = bproj[cbase + r];
#pragma unroll
      for (int ni = 0; ni < 4; ++ni) {
        int n = n0 + wn * 64 + ni * 16 + lo;
        out[((size_t)b * CDIM + cbase + r) * NTOK + n] = acc[mi][ni][r] + bias;
      }
    }
  }
}

extern "C" void kernel_launch(void* const* d_in, const int* in_sizes, int n_in,
                              void* d_out, int out_size, void* d_ws, size_t ws_size,
                              hipStream_t stream) {
  const float* x     = (const float*)d_in[0];
  const int*   fg    = (const int*)d_in[1];
  const float* Wqkv  = (const float*)d_in[2];
  const float* Wproj = (const float*)d_in[3];
  const float* bproj = (const float*)d_in[4];
  float* out = (float*)d_out;
  char* ws = (char*)d_ws;
  u16*   xbf  = (u16*)(ws);                    // 8388608 B
  u16*   Qm   = (u16*)(ws + 8388608);          // 8388608
  u16*   Km   = (u16*)(ws + 16777216);         // 8388608
  u16*   Vt   = (u16*)(ws + 25165824);         // 4*272*4096*2 = 8912896
  u16*   wq   = (u16*)(ws + 34078720);         // 393216
  u16*   wp   = (u16*)(ws + 34471936);         // 131072  -> ends 34603008
  u16*   pacc = (u16*)(ws + 34603008);         // 4 x 8 MiB bf16 = 33554432
  float2* pml = (float2*)(ws + 68157440);      // 512 KiB -> ends 68681728

  k_prep<<<1088, 256, 0, stream>>>(Wqkv, Wproj, fg, wq, wp, Vt);
  k_transpose<<<dim3(64, 4, 4), 256, 0, stream>>>(x, xbf);
  k_qkv<<<dim3(32, 6, 4), 256, 0, stream>>>(xbf, wq, fg, Qm, Km, Vt);
  k_attn<<<512, 256, 0, stream>>>(Qm, Km, Vt, pacc, pml, 2);
  k_proj<<<dim3(32, 2, 4), 256, 0, stream>>>(pacc, pml, wp, bproj, out);
}

// Round 12
// 183.611 us; speedup vs baseline: 1.5121x; 1.0195x over previous
//
#include <hip/hip_runtime.h>
#include <hip/hip_bf16.h>

#define BATCH 4
#define CDIM  256
#define NTOK  4096
#define THREE (3*CDIM)
#define VROWS 272   // 256 V channels + fg row at 256 (257..271 unused)

typedef unsigned short u16;
typedef __attribute__((ext_vector_type(4))) float f32x4;
typedef __attribute__((ext_vector_type(8))) short bf16x8;
typedef __attribute__((ext_vector_type(4))) unsigned int u32x4;

#define AS1 __attribute__((address_space(1)))
#define AS3 __attribute__((address_space(3)))

__device__ __forceinline__ u16 f2bf(float x) {
  unsigned int u = __float_as_uint(x);
  unsigned int r = (u + 0x7fffu + ((u >> 16) & 1u)) >> 16;   // RTNE
  return (u16)r;
}
__device__ __forceinline__ float bf2f(u16 v) {
  return __uint_as_float(((unsigned int)v) << 16);
}

__device__ __forceinline__ void gload_lds16(const u16* g, u16* l) {
  __builtin_amdgcn_global_load_lds((AS1 const void*)g, (AS3 void*)l, 16, 0, 0);
}

// ---------------- K1: weights -> bf16; fg -> bf16 row in Vt ----------------
__global__ void k_prep(const float* __restrict__ Wqkv, const float* __restrict__ Wproj,
                       const int* __restrict__ fg,
                       u16* __restrict__ wq, u16* __restrict__ wp,
                       u16* __restrict__ Vt) {
  int i = blockIdx.x * 256 + threadIdx.x;
  const int nq = THREE * CDIM;          // 196608
  const int np = CDIM * CDIM;           // 65536
  const int nf = BATCH * NTOK;          // 16384 (fg row c=256)
  if (i < nq) { wq[i] = f2bf(Wqkv[i]); return; }
  int j = i - nq;
  if (j < np) { wp[j] = f2bf(Wproj[j]); return; }
  int k = j - np;
  if (k < nf) {
    int b = k >> 12, key = k & (NTOK - 1);
    Vt[((size_t)b * VROWS + 256) * NTOK + key] = fg[k] ? 0x3F80 : 0;  // bf16 1.0/0.0
  }
}

// ---------------- K2: x [B][C][N] f32 -> xbf [B][N][C] bf16 ----------------
__global__ __launch_bounds__(256) void k_transpose(const float* __restrict__ x, u16* __restrict__ xbf) {
  __shared__ u16 t[64][65];
  int n0 = blockIdx.x * 64;
  int c0 = blockIdx.y * 64;
  int b  = blockIdx.z;
  int tid = threadIdx.x;
  const float* xp = x + (size_t)b * CDIM * NTOK;
  int nl = tid & 63;
  int cb = tid >> 6;
#pragma unroll
  for (int i = 0; i < 16; ++i) {
    int cl = cb * 16 + i;
    t[nl][cl] = f2bf(xp[(size_t)(c0 + cl) * NTOK + n0 + nl]);
  }
  __syncthreads();
  int cl = tid & 63;
  int nb = tid >> 6;
  u16* op = xbf + ((size_t)b * NTOK + n0) * CDIM + c0;
#pragma unroll
  for (int i = 0; i < 16; ++i) {
    int nl2 = nb * 16 + i;
    op[(size_t)nl2 * CDIM + cl] = t[nl2][cl];
  }
}

// ---------------- K3: qkv GEMM. Q (x log2e/16), K row-major; V^T [c][key], fg-zeroed ----------------
__global__ __launch_bounds__(256) void k_qkv(const u16* __restrict__ xbf, const u16* __restrict__ wq,
                                             const int* __restrict__ fg,
                                             u16* __restrict__ Qm, u16* __restrict__ Km,
                                             u16* __restrict__ Vt) {
  __shared__ u16 Al[128][72];
  __shared__ u16 Bl[128][72];
  int n0 = blockIdx.x * 128;
  int d0 = blockIdx.y * 128;
  int b  = blockIdx.z;
  int tid = threadIdx.x;
  int lane = tid & 63, w = tid >> 6;
  int lo = lane & 15, hi = lane >> 4;
  int wm = w >> 1, wn = w & 1;
  f32x4 acc[4][4] = {};
  const u16* Ab = xbf + ((size_t)b * NTOK + n0) * CDIM;
  const u16* Bb = wq + (size_t)d0 * CDIM;
  for (int kc = 0; kc < 256; kc += 64) {
    __syncthreads();
#pragma unroll
    for (int i = 0; i < 4; ++i) {
      int cid = i * 256 + tid;
      int row = cid >> 3, cc = cid & 7;
      *(uint4*)&Al[row][cc * 8] = *(const uint4*)(Ab + (size_t)row * CDIM + kc + cc * 8);
      *(uint4*)&Bl[row][cc * 8] = *(const uint4*)(Bb + (size_t)row * CDIM + kc + cc * 8);
    }
    __syncthreads();
#pragma unroll
    for (int kk = 0; kk < 2; ++kk) {
      bf16x8 af[4], bfr[4];
#pragma unroll
      for (int mi = 0; mi < 4; ++mi) af[mi]  = *(const bf16x8*)&Al[wm * 64 + mi * 16 + lo][kk * 32 + hi * 8];
#pragma unroll
      for (int ni = 0; ni < 4; ++ni) bfr[ni] = *(const bf16x8*)&Bl[wn * 64 + ni * 16 + lo][kk * 32 + hi * 8];
#pragma unroll
      for (int mi = 0; mi < 4; ++mi)
#pragma unroll
        for (int ni = 0; ni < 4; ++ni)
          acc[mi][ni] = __builtin_amdgcn_mfma_f32_16x16x32_bf16(af[mi], bfr[ni], acc[mi][ni], 0, 0, 0);
    }
  }
  int seg = d0 >> 8;   // 0=Q 1=K 2=V
  const float QSC = 0.0625f * 1.4426950408889634f;   // (1/sqrt(C)) * log2(e)
#pragma unroll
  for (int mi = 0; mi < 4; ++mi) {
    int nbase = n0 + wm * 64 + mi * 16 + hi * 4;
#pragma unroll
    for (int ni = 0; ni < 4; ++ni) {
      int d = d0 + wn * 64 + ni * 16 + lo;
      if (seg == 0) {
#pragma unroll
        for (int r = 0; r < 4; ++r)
          Qm[((size_t)b * NTOK + nbase + r) * CDIM + d] = f2bf(acc[mi][ni][r] * QSC);
      } else if (seg == 1) {
        int dk = d - 256;
#pragma unroll
        for (int r = 0; r < 4; ++r)
          Km[((size_t)b * NTOK + nbase + r) * CDIM + dk] = f2bf(acc[mi][ni][r]);
      } else {
        int dv = d - 512;
        ushort4 pk;
        pk.x = fg[b * NTOK + nbase + 0] ? f2bf(acc[mi][ni][0]) : (u16)0;
        pk.y = fg[b * NTOK + nbase + 1] ? f2bf(acc[mi][ni][1]) : (u16)0;
        pk.z = fg[b * NTOK + nbase + 2] ? f2bf(acc[mi][ni][2]) : (u16)0;
        pk.w = fg[b * NTOK + nbase + 3] ? f2bf(acc[mi][ni][3]) : (u16)0;
        *(ushort4*)&Vt[((size_t)b * VROWS + dv) * NTOK + nbase] = pk;
      }
    }
  }
}

// ---------------- K4: flash attention, swapped-operand QK + in-register P^T ----------------
// grid = 512 blocks; 4 waves x 32 q-rows; KBLK=32; double-buffered staging.
// S^T = mfma(K,Q): lane holds q=lo, keys=(ni,hi*4+r). P^T -> PV B-fragment built in
// registers via cvt_pk + shfl (no Pl LDS roundtrip). PV^T = mfma(V^T, P^T) -> acc
// holds out^T[d][q]. Fixed-max FM=12 (log2 domain); numerator mask via zeroed V rows;
// l = sum P*fg per q (lane-local, 2-shuffle reduce).
__global__ __launch_bounds__(256, 2) void k_attn(const u16* __restrict__ Qm, const u16* __restrict__ Km,
                                                 const u16* __restrict__ Vt,
                                                 u16* __restrict__ pacc, float2* __restrict__ pml,
                                                 int lsplit) {
  __shared__ u16 Kl[2][32 * 256];    // 16KB x2; row=512B, 16B-chunk ^= (row&7)<<4
  __shared__ u16 Vl[2][256 * 32];    // 16KB x2; row=64B (V^T [c][key]), chunk ^= row&3
  __shared__ u16 fgl[1024];          // bf16 fg for this chunk's 1024 keys
  const float FM = 12.0f;            // fixed softmax max (log2 units)
  int nwg = gridDim.x;
  int cpx = nwg >> 3;
  int orig = blockIdx.x;
  int wg = (orig & 7) * cpx + (orig >> 3);   // bijective XCD swizzle (nwg % 8 == 0)
  int qt = wg & 31;
  int bs = wg >> 5;
  int s_k = bs & ((1 << lsplit) - 1);
  int b   = bs >> lsplit;
  int chunk = NTOK >> lsplit;
  int koff  = s_k * chunk;
  int iters = chunk >> 5;

  int tid = threadIdx.x;
  int lane = tid & 63, w = tid >> 6;
  int lo = lane & 15, hi = lane >> 4;
  int n0 = qt * 128 + w * 32;
  // Q: 32 rows x 256 in registers (64 VGPR)
  bf16x8 qf[2][8];
#pragma unroll
  for (int s = 0; s < 2; ++s) {
    const u16* qp = Qm + ((size_t)b * NTOK + n0 + s * 16 + lo) * CDIM + hi * 8;
#pragma unroll
    for (int ks = 0; ks < 8; ++ks) qf[s][ks] = *(const bf16x8*)(qp + ks * 32);
  }
  f32x4 acc[2][16] = {};   // out^T: acc[s][cf][r] = out[d=cf*16+hi*4+r][q=s*16+lo]
  float lsum[2] = {0.0f, 0.0f};
  const u16* kbase = Km + (size_t)b * NTOK * CDIM;
  const u16* vbase = Vt + (size_t)b * VROWS * NTOK;
  const u16* fgrow = vbase + (size_t)256 * NTOK;   // bf16 fg row
  int kc  = lane & 31;   // K staging: 16B chunk within row pair
  int krp = lane >> 5;
  int vr  = lane >> 2;   // V staging: row within 16-row group
  int vc  = lane & 3;
  int srcA = lo + ((hi & 1) << 5);   // P^T exchange source lanes
  int srcB = srcA + 16;

  // stage K (4 insts/wave) and V (4 insts/wave) for key-block m0 into buffer buf
  auto stage = [&](int buf, int m0) {
    u16* kld = &Kl[buf][w * 2048];
#pragma unroll
    for (int j = 0; j < 4; ++j) {
      int row = w * 8 + j * 2 + krp;
      int sb = (kc * 16) ^ ((row & 7) << 4);
      gload_lds16(kbase + (size_t)(m0 + row) * CDIM + (sb >> 1), kld + j * 512);
    }
#pragma unroll
    for (int j = 0; j < 4; ++j) {
      int idx = j * 4 + w;                 // 0..15
      int r = idx * 16 + vr;
      int d = vc ^ (r & 3);
      gload_lds16(vbase + (size_t)r * NTOK + m0 + d * 8, &Vl[buf][idx * 512]);
    }
  };

  // prologue: fg chunk (waves 0,1) + tile 0; barrier drains all gload_lds
  if (w < 2) gload_lds16(fgrow + koff + w * 512 + lane * 8, &fgl[w * 512 + lane * 8]);
  stage(0, koff);
  __syncthreads();
  for (int it = 0; it < iters; ++it) {
    int cur = it & 1;
    int m0 = koff + it * 32;
    if (it + 1 < iters) stage(cur ^ 1, m0 + 32);   // prefetch next tile
    // S^T - FM = (Q K^T)^T - 12: A = K-frag, B = Q-frag (swapped operands)
    f32x4 sv[2][2];
#pragma unroll
    for (int s = 0; s < 2; ++s)
#pragma unroll
      for (int ni = 0; ni < 2; ++ni)
#pragma unroll
        for (int r = 0; r < 4; ++r) sv[s][ni][r] = -FM;
    __builtin_amdgcn_s_setprio(1);
#pragma unroll
    for (int ks = 0; ks < 8; ++ks) {
      bf16x8 kf[2];
#pragma unroll
      for (int ni = 0; ni < 2; ++ni) {
        int row = ni * 16 + lo;
        const char* kp = (const char*)&Kl[cur][0] + row * 512 + ((ks * 64 + hi * 16) ^ ((row & 7) << 4));
        kf[ni] = *(const bf16x8*)kp;
      }
#pragma unroll
      for (int s = 0; s < 2; ++s)
#pragma unroll
        for (int ni = 0; ni < 2; ++ni)
          sv[s][ni] = __builtin_amdgcn_mfma_f32_16x16x32_bf16(kf[ni], qf[s][ks], sv[s][ni], 0, 0, 0);
    }
    __builtin_amdgcn_s_setprio(0);
    // P = exp2(S^T - FM); lane covers keys {ni*16 + hi*4 + r} for q = s*16+lo.
    // l += P*fg (per-key mask from LDS, ushort4 per ni).
    float p0[2][2][4];
#pragma unroll
    for (int ni = 0; ni < 2; ++ni) {
      ushort4 fgu = *(const ushort4*)&fgl[it * 32 + ni * 16 + hi * 4];
      float fg0 = bf2f(fgu.x), fg1 = bf2f(fgu.y), fg2 = bf2f(fgu.z), fg3 = bf2f(fgu.w);
#pragma unroll
      for (int s = 0; s < 2; ++s) {
        float e0 = exp2f(sv[s][ni][0]);
        float e1 = exp2f(sv[s][ni][1]);
        float e2 = exp2f(sv[s][ni][2]);
        float e3 = exp2f(sv[s][ni][3]);
        lsum[s] += e0 * fg0 + e1 * fg1 + e2 * fg2 + e3 * fg3;
        p0[s][ni][0] = e0; p0[s][ni][1] = e1; p0[s][ni][2] = e2; p0[s][ni][3] = e3;
      }
    }
    // P^T -> PV B-fragment in registers: lane needs keys hi*8..hi*8+7 for its q.
    // src lanes: (lo, 2*(hi&1)) and (lo, 2*(hi&1)+1); ni half selected by own hi>>1.
    bf16x8 pbf[2];
#pragma unroll
    for (int s = 0; s < 2; ++s) {
      unsigned int pk00, pk01, pk10, pk11;
      asm("v_cvt_pk_bf16_f32 %0, %1, %2" : "=v"(pk00) : "v"(p0[s][0][0]), "v"(p0[s][0][1]));
      asm("v_cvt_pk_bf16_f32 %0, %1, %2" : "=v"(pk01) : "v"(p0[s][0][2]), "v"(p0[s][0][3]));
      asm("v_cvt_pk_bf16_f32 %0, %1, %2" : "=v"(pk10) : "v"(p0[s][1][0]), "v"(p0[s][1][1]));
      asm("v_cvt_pk_bf16_f32 %0, %1, %2" : "=v"(pk11) : "v"(p0[s][1][2]), "v"(p0[s][1][3]));
      int a00 = __shfl((int)pk00, srcA); int a10 = __shfl((int)pk10, srcA);
      int a01 = __shfl((int)pk01, srcA); int a11 = __shfl((int)pk11, srcA);
      int b00 = __shfl((int)pk00, srcB); int b10 = __shfl((int)pk10, srcB);
      int b01 = __shfl((int)pk01, srcB); int b11 = __shfl((int)pk11, srcB);
      u32x4 tv;
      tv.x = (unsigned)(hi < 2 ? a00 : a10);
      tv.y = (unsigned)(hi < 2 ? a01 : a11);
      tv.z = (unsigned)(hi < 2 ? b00 : b10);
      tv.w = (unsigned)(hi < 2 ? b01 : b11);
      pbf[s] = __builtin_bit_cast(bf16x8, tv);
    }
    // PV^T: A = V^T-frag (rows=d, k=keys hi*8+j — same vb read as before), B = P^T
    __builtin_amdgcn_s_setprio(1);
#pragma unroll
    for (int cf = 0; cf < 16; ++cf) {
      const char* vp = (const char*)&Vl[cur][0] + (cf * 16 + lo) * 64 + ((hi ^ (lo & 3)) << 4);
      bf16x8 vb = *(const bf16x8*)vp;
#pragma unroll
      for (int s = 0; s < 2; ++s)
        acc[s][cf] = __builtin_amdgcn_mfma_f32_16x16x32_bf16(vb, pbf[s], acc[s][cf], 0, 0, 0);
    }
    __builtin_amdgcn_s_setprio(0);
    __syncthreads();   // drains next-tile stage loads + all waves done with buf[cur]
  }
  // l reduction over the 4 hi-groups (lanes differing in bits 4,5 share q=lo)
  float ls[2];
#pragma unroll
  for (int s = 0; s < 2; ++s) {
    float t = lsum[s];
    t += __shfl_xor(t, 16);
    t += __shfl_xor(t, 32);
    ls[s] = t;
  }
  // epilogue: bf16 unnormalized partials (out^T regs -> row-major [q][d] stores) + (FM, l)
  u16* pb = pacc + (((size_t)s_k * BATCH + b) * NTOK + n0) * CDIM;
  float2* pm = pml + ((size_t)s_k * BATCH + b) * NTOK + n0;
#pragma unroll
  for (int s = 0; s < 2; ++s) {
#pragma unroll
    for (int cf = 0; cf < 16; ++cf) {
      ushort4 st;
      st.x = f2bf(acc[s][cf][0]);
      st.y = f2bf(acc[s][cf][1]);
      st.z = f2bf(acc[s][cf][2]);
      st.w = f2bf(acc[s][cf][3]);
      *(ushort4*)&pb[(size_t)(s * 16 + lo) * CDIM + cf * 16 + hi * 4] = st;
    }
    if (lane < 16) {
      float2 v; v.x = FM; v.y = ls[s];
      pm[s * 16 + lane] = v;
    }
  }
}

// ---------------- K5: fused combine + projection ----------------
// out[b][c][n] = b_proj[c] + sum_k h[b][n][k] Wp[c][k],  h = (sum_s pacc_s) / (sum_s l_s)
__global__ __launch_bounds__(256) void k_proj(const u16* __restrict__ pacc,
                                              const float2* __restrict__ pml,
                                              const u16* __restrict__ wp,
                                              const float* __restrict__ bproj, float* __restrict__ out) {
  __shared__ u16 Al[128][72];
  __shared__ u16 Bl[128][72];
  __shared__ float invl[128];
  const int RN = BATCH * NTOK;
  int n0 = blockIdx.x * 128;
  int c0 = blockIdx.y * 128;
  int b  = blockIdx.z;
  int tid = threadIdx.x;
  int lane = tid & 63, w = tid >> 6;
  int lo = lane & 15, hi = lane >> 4;
  int wm = w >> 1, wn = w & 1;
  if (tid < 128) {
    float d = 0.0f;
#pragma unroll
    for (int s = 0; s < 4; ++s)
      d += pml[(size_t)s * RN + (size_t)b * NTOK + n0 + tid].y;
    invl[tid] = 1.0f / d;
  }
  f32x4 acc[4][4] = {};
  const u16* Ab = wp + (size_t)c0 * CDIM;
  for (int kcs = 0; kcs < 256; kcs += 64) {
    __syncthreads();
#pragma unroll
    for (int i = 0; i < 4; ++i) {
      int cid = i * 256 + tid;
      int row = cid >> 3, cc = cid & 7;
      *(uint4*)&Al[row][cc * 8] = *(const uint4*)(Ab + (size_t)row * CDIM + kcs + cc * 8);
      // B: sum 4 bf16 splits of pacc, scale by 1/l, back to bf16
      size_t off = ((size_t)b * NTOK + n0 + row) * CDIM + kcs + cc * 8;
      float v[8] = {0, 0, 0, 0, 0, 0, 0, 0};
#pragma unroll
      for (int s = 0; s < 4; ++s) {
        uint4 u = *(const uint4*)(pacc + (size_t)s * RN * CDIM + off);
        const u16* pu = (const u16*)&u;
#pragma unroll
        for (int j = 0; j < 8; ++j) v[j] += bf2f(pu[j]);
      }
      float iv = invl[row];
      ushort4 o0, o1;
      o0.x = f2bf(v[0] * iv); o0.y = f2bf(v[1] * iv); o0.z = f2bf(v[2] * iv); o0.w = f2bf(v[3] * iv);
      o1.x = f2bf(v[4] * iv); o1.y = f2bf(v[5] * iv); o1.z = f2bf(v[6] * iv); o1.w = f2bf(v[7] * iv);
      *(ushort4*)&Bl[row][cc * 8]     = o0;
      *(ushort4*)&Bl[row][cc * 8 + 4] = o1;
    }
    __syncthreads();
#pragma unroll
    for (int kk = 0; kk < 2; ++kk) {
      bf16x8 af[4], bfr[4];
#pragma unroll
      for (int mi = 0; mi < 4; ++mi) af[mi]  = *(const bf16x8*)&Al[wm * 64 + mi * 16 + lo][kk * 32 + hi * 8];
#pragma unroll
      for (int ni = 0; ni < 4; ++ni) bfr[ni] = *(const bf16x8*)&Bl[wn * 64 + ni * 16 + lo][kk * 32 + hi * 8];
#pragma unroll
      for (int mi = 0; mi < 4; ++mi)
#pragma unroll
        for (int ni = 0; ni < 4; ++ni)
          acc[mi][ni] = __builtin_amdgcn_mfma_f32_16x16x32_bf16(af[mi], bfr[ni], acc[mi][ni], 0, 0, 0);
    }
  }
#pragma unroll
  for (int mi = 0; mi < 4; ++mi) {
    int cbase = c0 + wm * 64 + mi * 16 + hi * 4;
#pragma unroll
    for (int r = 0; r < 4; ++r) {
      float bias = bproj[cbase + r];
#pragma unroll
      for (int ni = 0; ni < 4; ++ni) {
        int n = n0 + wn * 64 + ni * 16 + lo;
        out[((size_t)b * CDIM + cbase + r) * NTOK + n] = acc[mi][ni][r] + bias;
      }
    }
  }
}

extern "C" void kernel_launch(void* const* d_in, const int* in_sizes, int n_in,
                              void* d_out, int out_size, void* d_ws, size_t ws_size,
                              hipStream_t stream) {
  const float* x     = (const float*)d_in[0];
  const int*   fg    = (const int*)d_in[1];
  const float* Wqkv  = (const float*)d_in[2];
  const float* Wproj = (const float*)d_in[3];
  const float* bproj = (const float*)d_in[4];
  float* out = (float*)d_out;
  char* ws = (char*)d_ws;
  u16*   xbf  = (u16*)(ws);                    // 8388608 B
  u16*   Qm   = (u16*)(ws + 8388608);          // 8388608
  u16*   Km   = (u16*)(ws + 16777216);         // 8388608
  u16*   Vt   = (u16*)(ws + 25165824);         // 4*272*4096*2 = 8912896
  u16*   wq   = (u16*)(ws + 34078720);         // 393216
  u16*   wp   = (u16*)(ws + 34471936);         // 131072  -> ends 34603008
  u16*   pacc = (u16*)(ws + 34603008);         // 4 x 8 MiB bf16 = 33554432
  float2* pml = (float2*)(ws + 68157440);      // 512 KiB -> ends 68681728

  k_prep<<<1088, 256, 0, stream>>>(Wqkv, Wproj, fg, wq, wp, Vt);
  k_transpose<<<dim3(64, 4, 4), 256, 0, stream>>>(x, xbf);
  k_qkv<<<dim3(32, 6, 4), 256, 0, stream>>>(xbf, wq, fg, Qm, Km, Vt);
  k_attn<<<512, 256, 0, stream>>>(Qm, Km, Vt, pacc, pml, 2);
  k_proj<<<dim3(32, 2, 4), 256, 0, stream>>>(pacc, pml, wp, bproj, out);
}

// Round 13
// 183.266 us; speedup vs baseline: 1.5149x; 1.0019x over previous
//
#include <hip/hip_runtime.h>
#include <hip/hip_bf16.h>

#define BATCH 4
#define CDIM  256
#define NTOK  4096
#define THREE (3*CDIM)
#define VROWS 272   // 256 V channels + fg row at 256 (257..271 unused)

typedef unsigned short u16;
typedef __attribute__((ext_vector_type(4))) float f32x4;
typedef __attribute__((ext_vector_type(8))) short bf16x8;
typedef __attribute__((ext_vector_type(4))) unsigned int u32x4;

#define AS1 __attribute__((address_space(1)))
#define AS3 __attribute__((address_space(3)))

__device__ __forceinline__ u16 f2bf(float x) {
  unsigned int u = __float_as_uint(x);
  unsigned int r = (u + 0x7fffu + ((u >> 16) & 1u)) >> 16;   // RTNE
  return (u16)r;
}
__device__ __forceinline__ float bf2f(u16 v) {
  return __uint_as_float(((unsigned int)v) << 16);
}

__device__ __forceinline__ void gload_lds16(const u16* g, u16* l) {
  __builtin_amdgcn_global_load_lds((AS1 const void*)g, (AS3 void*)l, 16, 0, 0);
}

// ---------------- K1: weights -> bf16; fg -> bf16 row in Vt ----------------
__global__ void k_prep(const float* __restrict__ Wqkv, const float* __restrict__ Wproj,
                       const int* __restrict__ fg,
                       u16* __restrict__ wq, u16* __restrict__ wp,
                       u16* __restrict__ Vt) {
  int i = blockIdx.x * 256 + threadIdx.x;
  const int nq = THREE * CDIM;          // 196608
  const int np = CDIM * CDIM;           // 65536
  const int nf = BATCH * NTOK;          // 16384 (fg row c=256)
  if (i < nq) { wq[i] = f2bf(Wqkv[i]); return; }
  int j = i - nq;
  if (j < np) { wp[j] = f2bf(Wproj[j]); return; }
  int k = j - np;
  if (k < nf) {
    int b = k >> 12, key = k & (NTOK - 1);
    Vt[((size_t)b * VROWS + 256) * NTOK + key] = fg[k] ? 0x3F80 : 0;  // bf16 1.0/0.0
  }
}

// ---------------- K2: x [B][C][N] f32 -> xbf [B][N][C] bf16 ----------------
__global__ __launch_bounds__(256) void k_transpose(const float* __restrict__ x, u16* __restrict__ xbf) {
  __shared__ u16 t[64][65];
  int n0 = blockIdx.x * 64;
  int c0 = blockIdx.y * 64;
  int b  = blockIdx.z;
  int tid = threadIdx.x;
  const float* xp = x + (size_t)b * CDIM * NTOK;
  int nl = tid & 63;
  int cb = tid >> 6;
#pragma unroll
  for (int i = 0; i < 16; ++i) {
    int cl = cb * 16 + i;
    t[nl][cl] = f2bf(xp[(size_t)(c0 + cl) * NTOK + n0 + nl]);
  }
  __syncthreads();
  int cl = tid & 63;
  int nb = tid >> 6;
  u16* op = xbf + ((size_t)b * NTOK + n0) * CDIM + c0;
#pragma unroll
  for (int i = 0; i < 16; ++i) {
    int nl2 = nb * 16 + i;
    op[(size_t)nl2 * CDIM + cl] = t[nl2][cl];
  }
}

// ---------------- K3: qkv GEMM. Q (x log2e/16), K row-major; V^T [c][key], fg-zeroed ----------------
__global__ __launch_bounds__(256) void k_qkv(const u16* __restrict__ xbf, const u16* __restrict__ wq,
                                             const int* __restrict__ fg,
                                             u16* __restrict__ Qm, u16* __restrict__ Km,
                                             u16* __restrict__ Vt) {
  __shared__ u16 Al[128][72];
  __shared__ u16 Bl[128][72];
  int n0 = blockIdx.x * 128;
  int d0 = blockIdx.y * 128;
  int b  = blockIdx.z;
  int tid = threadIdx.x;
  int lane = tid & 63, w = tid >> 6;
  int lo = lane & 15, hi = lane >> 4;
  int wm = w >> 1, wn = w & 1;
  f32x4 acc[4][4] = {};
  const u16* Ab = xbf + ((size_t)b * NTOK + n0) * CDIM;
  const u16* Bb = wq + (size_t)d0 * CDIM;
  for (int kc = 0; kc < 256; kc += 64) {
    __syncthreads();
#pragma unroll
    for (int i = 0; i < 4; ++i) {
      int cid = i * 256 + tid;
      int row = cid >> 3, cc = cid & 7;
      *(uint4*)&Al[row][cc * 8] = *(const uint4*)(Ab + (size_t)row * CDIM + kc + cc * 8);
      *(uint4*)&Bl[row][cc * 8] = *(const uint4*)(Bb + (size_t)row * CDIM + kc + cc * 8);
    }
    __syncthreads();
#pragma unroll
    for (int kk = 0; kk < 2; ++kk) {
      bf16x8 af[4], bfr[4];
#pragma unroll
      for (int mi = 0; mi < 4; ++mi) af[mi]  = *(const bf16x8*)&Al[wm * 64 + mi * 16 + lo][kk * 32 + hi * 8];
#pragma unroll
      for (int ni = 0; ni < 4; ++ni) bfr[ni] = *(const bf16x8*)&Bl[wn * 64 + ni * 16 + lo][kk * 32 + hi * 8];
#pragma unroll
      for (int mi = 0; mi < 4; ++mi)
#pragma unroll
        for (int ni = 0; ni < 4; ++ni)
          acc[mi][ni] = __builtin_amdgcn_mfma_f32_16x16x32_bf16(af[mi], bfr[ni], acc[mi][ni], 0, 0, 0);
    }
  }
  int seg = d0 >> 8;   // 0=Q 1=K 2=V
  const float QSC = 0.0625f * 1.4426950408889634f;   // (1/sqrt(C)) * log2(e)
#pragma unroll
  for (int mi = 0; mi < 4; ++mi) {
    int nbase = n0 + wm * 64 + mi * 16 + hi * 4;
#pragma unroll
    for (int ni = 0; ni < 4; ++ni) {
      int d = d0 + wn * 64 + ni * 16 + lo;
      if (seg == 0) {
#pragma unroll
        for (int r = 0; r < 4; ++r)
          Qm[((size_t)b * NTOK + nbase + r) * CDIM + d] = f2bf(acc[mi][ni][r] * QSC);
      } else if (seg == 1) {
        int dk = d - 256;
#pragma unroll
        for (int r = 0; r < 4; ++r)
          Km[((size_t)b * NTOK + nbase + r) * CDIM + dk] = f2bf(acc[mi][ni][r]);
      } else {
        int dv = d - 512;
        ushort4 pk;
        pk.x = fg[b * NTOK + nbase + 0] ? f2bf(acc[mi][ni][0]) : (u16)0;
        pk.y = fg[b * NTOK + nbase + 1] ? f2bf(acc[mi][ni][1]) : (u16)0;
        pk.z = fg[b * NTOK + nbase + 2] ? f2bf(acc[mi][ni][2]) : (u16)0;
        pk.w = fg[b * NTOK + nbase + 3] ? f2bf(acc[mi][ni][3]) : (u16)0;
        *(ushort4*)&Vt[((size_t)b * VROWS + dv) * NTOK + nbase] = pk;
      }
    }
  }
}

// ---------------- K4: flash attention, swapped-operand QK + in-register P^T ----------------
// grid = 512 blocks; 4 waves x 32 q-rows; KBLK=32; double-buffered staging.
// S^T = mfma(K,Q); P^T built in registers via cvt_pk + shfl; PV^T = mfma(V^T, P^T).
// V swizzle g(row) = (row&3) ^ ((row>>2)&3): per 8 consecutive reader lanes the
// 16B bank-windows enumerate all 8 values once (was 4-way with g = row&3).
__global__ __launch_bounds__(256, 2) void k_attn(const u16* __restrict__ Qm, const u16* __restrict__ Km,
                                                 const u16* __restrict__ Vt,
                                                 u16* __restrict__ pacc, float2* __restrict__ pml,
                                                 int lsplit) {
  __shared__ u16 Kl[2][32 * 256];    // 16KB x2; row=512B, 16B-chunk ^= (row&7)
  __shared__ u16 Vl[2][256 * 32];    // 16KB x2; row=64B, chunk ^= (row&3)^((row>>2)&3)
  __shared__ u16 fgl[1024];          // bf16 fg for this chunk's 1024 keys
  const float FM = 12.0f;            // fixed softmax max (log2 units)
  int nwg = gridDim.x;
  int cpx = nwg >> 3;
  int orig = blockIdx.x;
  int wg = (orig & 7) * cpx + (orig >> 3);   // bijective XCD swizzle (nwg % 8 == 0)
  int qt = wg & 31;
  int bs = wg >> 5;
  int s_k = bs & ((1 << lsplit) - 1);
  int b   = bs >> lsplit;
  int chunk = NTOK >> lsplit;
  int koff  = s_k * chunk;
  int iters = chunk >> 5;

  int tid = threadIdx.x;
  int lane = tid & 63, w = tid >> 6;
  int lo = lane & 15, hi = lane >> 4;
  int n0 = qt * 128 + w * 32;
  // Q: 32 rows x 256 in registers (64 VGPR)
  bf16x8 qf[2][8];
#pragma unroll
  for (int s = 0; s < 2; ++s) {
    const u16* qp = Qm + ((size_t)b * NTOK + n0 + s * 16 + lo) * CDIM + hi * 8;
#pragma unroll
    for (int ks = 0; ks < 8; ++ks) qf[s][ks] = *(const bf16x8*)(qp + ks * 32);
  }
  f32x4 acc[2][16] = {};   // out^T: acc[s][cf][r] = out[d=cf*16+hi*4+r][q=s*16+lo]
  float lsum[2] = {0.0f, 0.0f};
  const u16* kbase = Km + (size_t)b * NTOK * CDIM;
  const u16* vbase = Vt + (size_t)b * VROWS * NTOK;
  const u16* fgrow = vbase + (size_t)256 * NTOK;   // bf16 fg row
  int kc  = lane & 31;   // K staging: 16B chunk within row pair
  int krp = lane >> 5;
  int vr  = lane >> 2;   // V staging: row within 16-row group
  int vc  = lane & 3;
  int srcA = lo + ((hi & 1) << 5);   // P^T exchange source lanes
  int srcB = srcA + 16;

  // stage K (4 insts/wave) and V (4 insts/wave) for key-block m0 into buffer buf
  auto stage = [&](int buf, int m0) {
    u16* kld = &Kl[buf][w * 2048];
#pragma unroll
    for (int j = 0; j < 4; ++j) {
      int row = w * 8 + j * 2 + krp;
      int sb = (kc * 16) ^ ((row & 7) << 4);
      gload_lds16(kbase + (size_t)(m0 + row) * CDIM + (sb >> 1), kld + j * 512);
    }
#pragma unroll
    for (int j = 0; j < 4; ++j) {
      int idx = j * 4 + w;                 // 0..15
      int r = idx * 16 + vr;
      int d = vc ^ (r & 3) ^ ((r >> 2) & 3);   // full-window source swizzle
      gload_lds16(vbase + (size_t)r * NTOK + m0 + d * 8, &Vl[buf][idx * 512]);
    }
  };

  // prologue: fg chunk (waves 0,1) + tile 0; barrier drains all gload_lds
  if (w < 2) gload_lds16(fgrow + koff + w * 512 + lane * 8, &fgl[w * 512 + lane * 8]);
  stage(0, koff);
  __syncthreads();
  for (int it = 0; it < iters; ++it) {
    int cur = it & 1;
    int m0 = koff + it * 32;
    if (it + 1 < iters) stage(cur ^ 1, m0 + 32);   // prefetch next tile
    // S^T - FM = (Q K^T)^T - 12: A = K-frag, B = Q-frag (swapped operands)
    f32x4 sv[2][2];
#pragma unroll
    for (int s = 0; s < 2; ++s)
#pragma unroll
      for (int ni = 0; ni < 2; ++ni)
#pragma unroll
        for (int r = 0; r < 4; ++r) sv[s][ni][r] = -FM;
    __builtin_amdgcn_s_setprio(1);
#pragma unroll
    for (int ks = 0; ks < 8; ++ks) {
      bf16x8 kf[2];
#pragma unroll
      for (int ni = 0; ni < 2; ++ni) {
        int row = ni * 16 + lo;
        const char* kp = (const char*)&Kl[cur][0] + row * 512 + ((ks * 64 + hi * 16) ^ ((row & 7) << 4));
        kf[ni] = *(const bf16x8*)kp;
      }
#pragma unroll
      for (int s = 0; s < 2; ++s)
#pragma unroll
        for (int ni = 0; ni < 2; ++ni)
          sv[s][ni] = __builtin_amdgcn_mfma_f32_16x16x32_bf16(kf[ni], qf[s][ks], sv[s][ni], 0, 0, 0);
    }
    __builtin_amdgcn_s_setprio(0);
    // P = exp2(S^T - FM); lane covers keys {ni*16 + hi*4 + r} for q = s*16+lo.
    // l += P*fg (per-key mask from LDS, ushort4 per ni).
    float p0[2][2][4];
#pragma unroll
    for (int ni = 0; ni < 2; ++ni) {
      ushort4 fgu = *(const ushort4*)&fgl[it * 32 + ni * 16 + hi * 4];
      float fg0 = bf2f(fgu.x), fg1 = bf2f(fgu.y), fg2 = bf2f(fgu.z), fg3 = bf2f(fgu.w);
#pragma unroll
      for (int s = 0; s < 2; ++s) {
        float e0 = exp2f(sv[s][ni][0]);
        float e1 = exp2f(sv[s][ni][1]);
        float e2 = exp2f(sv[s][ni][2]);
        float e3 = exp2f(sv[s][ni][3]);
        lsum[s] += e0 * fg0 + e1 * fg1 + e2 * fg2 + e3 * fg3;
        p0[s][ni][0] = e0; p0[s][ni][1] = e1; p0[s][ni][2] = e2; p0[s][ni][3] = e3;
      }
    }
    // P^T -> PV B-fragment in registers: lane needs keys hi*8..hi*8+7 for its q.
    bf16x8 pbf[2];
#pragma unroll
    for (int s = 0; s < 2; ++s) {
      unsigned int pk00, pk01, pk10, pk11;
      asm("v_cvt_pk_bf16_f32 %0, %1, %2" : "=v"(pk00) : "v"(p0[s][0][0]), "v"(p0[s][0][1]));
      asm("v_cvt_pk_bf16_f32 %0, %1, %2" : "=v"(pk01) : "v"(p0[s][0][2]), "v"(p0[s][0][3]));
      asm("v_cvt_pk_bf16_f32 %0, %1, %2" : "=v"(pk10) : "v"(p0[s][1][0]), "v"(p0[s][1][1]));
      asm("v_cvt_pk_bf16_f32 %0, %1, %2" : "=v"(pk11) : "v"(p0[s][1][2]), "v"(p0[s][1][3]));
      int a00 = __shfl((int)pk00, srcA); int a10 = __shfl((int)pk10, srcA);
      int a01 = __shfl((int)pk01, srcA); int a11 = __shfl((int)pk11, srcA);
      int b00 = __shfl((int)pk00, srcB); int b10 = __shfl((int)pk10, srcB);
      int b01 = __shfl((int)pk01, srcB); int b11 = __shfl((int)pk11, srcB);
      u32x4 tv;
      tv.x = (unsigned)(hi < 2 ? a00 : a10);
      tv.y = (unsigned)(hi < 2 ? a01 : a11);
      tv.z = (unsigned)(hi < 2 ? b00 : b10);
      tv.w = (unsigned)(hi < 2 ? b01 : b11);
      pbf[s] = __builtin_bit_cast(bf16x8, tv);
    }
    // PV^T: A = V^T-frag (rows=d, k=keys hi*8+j), B = P^T
    __builtin_amdgcn_s_setprio(1);
#pragma unroll
    for (int cf = 0; cf < 16; ++cf) {
      int row = cf * 16 + lo;
      const char* vp = (const char*)&Vl[cur][0] + row * 64 + ((hi ^ (lo & 3) ^ ((lo >> 2) & 3)) << 4);
      bf16x8 vb = *(const bf16x8*)vp;
#pragma unroll
      for (int s = 0; s < 2; ++s)
        acc[s][cf] = __builtin_amdgcn_mfma_f32_16x16x32_bf16(vb, pbf[s], acc[s][cf], 0, 0, 0);
    }
    __builtin_amdgcn_s_setprio(0);
    __syncthreads();   // drains next-tile stage loads + all waves done with buf[cur]
  }
  // l reduction over the 4 hi-groups (lanes differing in bits 4,5 share q=lo)
  float ls[2];
#pragma unroll
  for (int s = 0; s < 2; ++s) {
    float t = lsum[s];
    t += __shfl_xor(t, 16);
    t += __shfl_xor(t, 32);
    ls[s] = t;
  }
  // epilogue: bf16 unnormalized partials (out^T regs -> row-major [q][d] stores) + (FM, l)
  u16* pb = pacc + (((size_t)s_k * BATCH + b) * NTOK + n0) * CDIM;
  float2* pm = pml + ((size_t)s_k * BATCH + b) * NTOK + n0;
#pragma unroll
  for (int s = 0; s < 2; ++s) {
#pragma unroll
    for (int cf = 0; cf < 16; ++cf) {
      ushort4 st;
      st.x = f2bf(acc[s][cf][0]);
      st.y = f2bf(acc[s][cf][1]);
      st.z = f2bf(acc[s][cf][2]);
      st.w = f2bf(acc[s][cf][3]);
      *(ushort4*)&pb[(size_t)(s * 16 + lo) * CDIM + cf * 16 + hi * 4] = st;
    }
    if (lane < 16) {
      float2 v; v.x = FM; v.y = ls[s];
      pm[s * 16 + lane] = v;
    }
  }
}

// ---------------- K5: fused combine + projection ----------------
// out[b][c][n] = b_proj[c] + sum_k h[b][n][k] Wp[c][k],  h = (sum_s pacc_s) / (sum_s l_s)
__global__ __launch_bounds__(256) void k_proj(const u16* __restrict__ pacc,
                                              const float2* __restrict__ pml,
                                              const u16* __restrict__ wp,
                                              const float* __restrict__ bproj, float* __restrict__ out) {
  __shared__ u16 Al[128][72];
  __shared__ u16 Bl[128][72];
  __shared__ float invl[128];
  const int RN = BATCH * NTOK;
  int n0 = blockIdx.x * 128;
  int c0 = blockIdx.y * 128;
  int b  = blockIdx.z;
  int tid = threadIdx.x;
  int lane = tid & 63, w = tid >> 6;
  int lo = lane & 15, hi = lane >> 4;
  int wm = w >> 1, wn = w & 1;
  if (tid < 128) {
    float d = 0.0f;
#pragma unroll
    for (int s = 0; s < 4; ++s)
      d += pml[(size_t)s * RN + (size_t)b * NTOK + n0 + tid].y;
    invl[tid] = 1.0f / d;
  }
  f32x4 acc[4][4] = {};
  const u16* Ab = wp + (size_t)c0 * CDIM;
  for (int kcs = 0; kcs < 256; kcs += 64) {
    __syncthreads();
#pragma unroll
    for (int i = 0; i < 4; ++i) {
      int cid = i * 256 + tid;
      int row = cid >> 3, cc = cid & 7;
      *(uint4*)&Al[row][cc * 8] = *(const uint4*)(Ab + (size_t)row * CDIM + kcs + cc * 8);
      // B: sum 4 bf16 splits of pacc, scale by 1/l, back to bf16
      size_t off = ((size_t)b * NTOK + n0 + row) * CDIM + kcs + cc * 8;
      float v[8] = {0, 0, 0, 0, 0, 0, 0, 0};
#pragma unroll
      for (int s = 0; s < 4; ++s) {
        uint4 u = *(const uint4*)(pacc + (size_t)s * RN * CDIM + off);
        const u16* pu = (const u16*)&u;
#pragma unroll
        for (int j = 0; j < 8; ++j) v[j] += bf2f(pu[j]);
      }
      float iv = invl[row];
      ushort4 o0, o1;
      o0.x = f2bf(v[0] * iv); o0.y = f2bf(v[1] * iv); o0.z = f2bf(v[2] * iv); o0.w = f2bf(v[3] * iv);
      o1.x = f2bf(v[4] * iv); o1.y = f2bf(v[5] * iv); o1.z = f2bf(v[6] * iv); o1.w = f2bf(v[7] * iv);
      *(ushort4*)&Bl[row][cc * 8]     = o0;
      *(ushort4*)&Bl[row][cc * 8 + 4] = o1;
    }
    __syncthreads();
#pragma unroll
    for (int kk = 0; kk < 2; ++kk) {
      bf16x8 af[4], bfr[4];
#pragma unroll
      for (int mi = 0; mi < 4; ++mi) af[mi]  = *(const bf16x8*)&Al[wm * 64 + mi * 16 + lo][kk * 32 + hi * 8];
#pragma unroll
      for (int ni = 0; ni < 4; ++ni) bfr[ni] = *(const bf16x8*)&Bl[wn * 64 + ni * 16 + lo][kk * 32 + hi * 8];
#pragma unroll
      for (int mi = 0; mi < 4; ++mi)
#pragma unroll
        for (int ni = 0; ni < 4; ++ni)
          acc[mi][ni] = __builtin_amdgcn_mfma_f32_16x16x32_bf16(af[mi], bfr[ni], acc[mi][ni], 0, 0, 0);
    }
  }
#pragma unroll
  for (int mi = 0; mi < 4; ++mi) {
    int cbase = c0 + wm * 64 + mi * 16 + hi * 4;
#pragma unroll
    for (int r = 0; r < 4; ++r) {
      float bias = bproj[cbase + r];
#pragma unroll
      for (int ni = 0; ni < 4; ++ni) {
        int n = n0 + wn * 64 + ni * 16 + lo;
        out[((size_t)b * CDIM + cbase + r) * NTOK + n] = acc[mi][ni][r] + bias;
      }
    }
  }
}

extern "C" void kernel_launch(void* const* d_in, const int* in_sizes, int n_in,
                              void* d_out, int out_size, void* d_ws, size_t ws_size,
                              hipStream_t stream) {
  const float* x     = (const float*)d_in[0];
  const int*   fg    = (const int*)d_in[1];
  const float* Wqkv  = (const float*)d_in[2];
  const float* Wproj = (const float*)d_in[3];
  const float* bproj = (const float*)d_in[4];
  float* out = (float*)d_out;
  char* ws = (char*)d_ws;
  u16*   xbf  = (u16*)(ws);                    // 8388608 B
  u16*   Qm   = (u16*)(ws + 8388608);          // 8388608
  u16*   Km   = (u16*)(ws + 16777216);         // 8388608
  u16*   Vt   = (u16*)(ws + 25165824);         // 4*272*4096*2 = 8912896
  u16*   wq   = (u16*)(ws + 34078720);         // 393216
  u16*   wp   = (u16*)(ws + 34471936);         // 131072  -> ends 34603008
  u16*   pacc = (u16*)(ws + 34603008);         // 4 x 8 MiB bf16 = 33554432
  float2* pml = (float2*)(ws + 68157440);      // 512 KiB -> ends 68681728

  k_prep<<<1088, 256, 0, stream>>>(Wqkv, Wproj, fg, wq, wp, Vt);
  k_transpose<<<dim3(64, 4, 4), 256, 0, stream>>>(x, xbf);
  k_qkv<<<dim3(32, 6, 4), 256, 0, stream>>>(xbf, wq, fg, Qm, Km, Vt);
  k_attn<<<512, 256, 0, stream>>>(Qm, Km, Vt, pacc, pml, 2);
  k_proj<<<dim3(32, 2, 4), 256, 0, stream>>>(pacc, pml, wp, bproj, out);
}